// Round 3
// 595.501 us; speedup vs baseline: 1.0052x; 1.0052x over previous
//
#include <hip/hip_runtime.h>
#include <math.h>

// Problem constants
#define BQ    4
#define NTOT  13125
#define DD    256
#define NHH   8
#define FFD   1024
#define EPSLN 1e-5f
#define MROWS (BQ * NTOT)        // 52500
#define MPAD  52736              // 412*128

typedef __bf16 bf16_t;
typedef bf16_t bf16x8 __attribute__((ext_vector_type(8)));
typedef float floatx4 __attribute__((ext_vector_type(4)));

__device__ __forceinline__ unsigned short f2bf(float f) {
    unsigned u = __float_as_uint(f);
    return (unsigned short)((u + 0x7FFFu + ((u >> 16) & 1u)) >> 16);
}
__device__ __forceinline__ float bf2f(unsigned short h) {
    return __uint_as_float(((unsigned)h) << 16);
}

typedef const __attribute__((address_space(1))) unsigned int* gptr_t;
typedef __attribute__((address_space(3))) unsigned int* lptr_t;
__device__ __forceinline__ void gld16(const void* g, void* l) {
    __builtin_amdgcn_global_load_lds((gptr_t)g, (lptr_t)l, 16, 0, 0);
}

enum { EPI_F32 = 0, EPI_GELU = 2, EPI_VALSEG = 3 };

// Map padded concatenated feature row -> value-buffer row (b*NTOT + loff + nl)
__device__ __forceinline__ int val_row(int gm) {
    if (gm < 40064) {
        if (gm >= 40000) return -1;
        int b = gm / 10000; int nl = gm - b * 10000;
        return b * NTOT + nl;
    } else if (gm < 50176) {
        int r = gm - 40064;
        if (r >= 10000) return -1;
        int b = r / 2500; int nl = r - b * 2500;
        return b * NTOT + 10000 + nl;
    } else {
        int r = gm - 50176;
        if (r >= 2500) return -1;
        int b = r / 625; int nl = r - b * 625;
        return b * NTOT + 12500 + nl;
    }
}

// ---------------------------------------------------------------------------
// bf16 MFMA GEMM (m97 structure): A [Mpad,K] bf16, Bt [Npad,K] bf16.
// 128x128 tile, BK=32, 4 waves, 4x4 grid of 16x16x32 mfma.
// ---------------------------------------------------------------------------
template <int EPI, typename OutT>
__launch_bounds__(256)
__global__ void mm_k(const unsigned short* __restrict__ A,
                     const unsigned short* __restrict__ Bt,
                     const float* __restrict__ bias, OutT* __restrict__ C,
                     int M, int K, int Nout, int ldc, int Mstore) {
    __shared__ __align__(16) unsigned short As[128 * 32];
    __shared__ __align__(16) unsigned short Bs[128 * 32];

    const int tid = threadIdx.x;
    const int m0 = blockIdx.x * 128;
    const int n0 = blockIdx.y * 128;
    const int w = tid >> 6, lane = tid & 63;
    const int q = lane >> 4, l15 = lane & 15;
    const int wm = (w & 1) * 64, wn = (w >> 1) * 64;

    const int sr = tid >> 2;
    const int sk = (tid & 3) * 8;

    const unsigned short* Ag = A + (size_t)(m0 + sr) * K + sk;
    const unsigned short* Bg = Bt + (size_t)(n0 + sr) * K + sk;
    char* AsB = (char*)As;
    char* BsB = (char*)Bs;

    floatx4 acc[4][4];
#pragma unroll
    for (int t = 0; t < 4; t++)
#pragma unroll
        for (int u = 0; u < 4; u++) {
            floatx4 z = {0.f, 0.f, 0.f, 0.f};
            acc[t][u] = z;
        }

    for (int k0 = 0; k0 < K; k0 += 32) {
        gld16(Ag + k0, AsB + tid * 16);
        gld16(Ag + (size_t)64 * K + k0, AsB + 4096 + tid * 16);
        gld16(Bg + k0, BsB + tid * 16);
        gld16(Bg + (size_t)64 * K + k0, BsB + 4096 + tid * 16);
        __syncthreads();

        bf16x8 af[4], bfr[4];
#pragma unroll
        for (int t = 0; t < 4; t++)
            af[t] = *reinterpret_cast<const bf16x8*>(&As[(wm + t * 16 + l15) * 32 + q * 8]);
#pragma unroll
        for (int u = 0; u < 4; u++)
            bfr[u] = *reinterpret_cast<const bf16x8*>(&Bs[(wn + u * 16 + l15) * 32 + q * 8]);
#pragma unroll
        for (int t = 0; t < 4; t++)
#pragma unroll
            for (int u = 0; u < 4; u++)
                acc[t][u] = __builtin_amdgcn_mfma_f32_16x16x32_bf16(af[t], bfr[u], acc[t][u], 0, 0, 0);
        __syncthreads();
    }

    float bias_v[4];
#pragma unroll
    for (int u = 0; u < 4; u++) {
        int gn = n0 + wn + u * 16 + l15;
        bias_v[u] = (gn < Nout) ? bias[gn] : 0.f;
    }

#pragma unroll
    for (int t = 0; t < 4; t++) {
#pragma unroll
        for (int r = 0; r < 4; r++) {
            int gm = m0 + wm + t * 16 + q * 4 + r;
            int orow = gm;
            if (EPI == EPI_VALSEG) orow = val_row(gm);
#pragma unroll
            for (int u = 0; u < 4; u++) {
                int gn = n0 + wn + u * 16 + l15;
                if (gn >= Nout) continue;
                float v = acc[t][u][r] + bias_v[u];
                if (EPI == EPI_GELU) {
                    v = 0.5f * v * (1.f + erff(v * 0.70710678118f));
                    if (gm < Mstore) {
                        float ov = (gm < M) ? v : 0.f;
                        ((unsigned short*)C)[(size_t)gm * ldc + gn] = f2bf(ov);
                    }
                } else if (EPI == EPI_VALSEG) {
                    if (orow >= 0)
                        ((unsigned short*)C)[(size_t)orow * ldc + gn] = f2bf(v);
                } else {
                    if (gm < M) ((float*)C)[(size_t)gm * ldc + gn] = v;
                }
            }
        }
    }
}

// ---------------------------------------------------------------------------
// Fused GEMM (N=256) + bias + residual + LayerNorm.
// Tile 64 rows x 256 cols (full row), 4 waves col-split 64 each.
// RT: residual dtype (float or ushort/bf16); OT: output (ushort/bf16 or float).
// ---------------------------------------------------------------------------
template <typename RT, typename OT>
__launch_bounds__(256)
__global__ void gemmln_k(const unsigned short* __restrict__ A,
                         const unsigned short* __restrict__ Bt,
                         const float* __restrict__ bias, const RT* __restrict__ res,
                         const float* __restrict__ g, const float* __restrict__ be,
                         OT* __restrict__ out, int M, int K) {
    __shared__ __align__(16) unsigned short As[64 * 32];    // 4 KB
    __shared__ __align__(16) unsigned short Bs[256 * 32];   // 16 KB

    const int tid = threadIdx.x;
    const int m0 = blockIdx.x * 64;
    const int w = tid >> 6, lane = tid & 63;
    const int q = lane >> 4, l15 = lane & 15;
    const int wn = w * 64;

    const int sr = tid >> 2;
    const int sk = (tid & 3) * 8;
    const unsigned short* Ag = A + (size_t)(m0 + sr) * K + sk;
    const unsigned short* Bg = Bt + (size_t)sr * K + sk;
    char* AsB = (char*)As;
    char* BsB = (char*)Bs;

    floatx4 acc[4][4];
#pragma unroll
    for (int t = 0; t < 4; t++)
#pragma unroll
        for (int u = 0; u < 4; u++) {
            floatx4 z = {0.f, 0.f, 0.f, 0.f};
            acc[t][u] = z;
        }

    for (int k0 = 0; k0 < K; k0 += 32) {
        gld16(Ag + k0, AsB + tid * 16);
#pragma unroll
        for (int j = 0; j < 4; j++)
            gld16(Bg + (size_t)j * 64 * K + k0, BsB + j * 4096 + tid * 16);
        __syncthreads();

        bf16x8 af[4], bfr[4];
#pragma unroll
        for (int t = 0; t < 4; t++)
            af[t] = *reinterpret_cast<const bf16x8*>(&As[(t * 16 + l15) * 32 + q * 8]);
#pragma unroll
        for (int u = 0; u < 4; u++)
            bfr[u] = *reinterpret_cast<const bf16x8*>(&Bs[(wn + u * 16 + l15) * 32 + q * 8]);
#pragma unroll
        for (int t = 0; t < 4; t++)
#pragma unroll
            for (int u = 0; u < 4; u++)
                acc[t][u] = __builtin_amdgcn_mfma_f32_16x16x32_bf16(af[t], bfr[u], acc[t][u], 0, 0, 0);
        __syncthreads();
    }
    // after final sync: all LDS frag reads done; reuse As for row stats.

    float gg[4], bb[4], bias_v[4];
#pragma unroll
    for (int u = 0; u < 4; u++) {
        int gn = wn + u * 16 + l15;
        gg[u] = g[gn]; bb[u] = be[gn]; bias_v[u] = bias[gn];
    }

    float x[4][4][4];     // [t][r][u]
    float ssum[4][4], ssq[4][4];
#pragma unroll
    for (int t = 0; t < 4; t++) {
#pragma unroll
        for (int r = 0; r < 4; r++) {
            int gm = m0 + t * 16 + q * 4 + r;
            bool valid = gm < M;
            float s = 0.f, sq = 0.f;
#pragma unroll
            for (int u = 0; u < 4; u++) {
                int gn = wn + u * 16 + l15;
                float rv = 0.f;
                if (valid) {
                    if (sizeof(RT) == 2)
                        rv = bf2f(((const unsigned short*)res)[(size_t)gm * DD + gn]);
                    else
                        rv = ((const float*)res)[(size_t)gm * DD + gn];
                }
                float xx = acc[t][u][r] + bias_v[u] + rv;
                x[t][r][u] = xx;
                s += xx; sq += xx * xx;
            }
            ssum[t][r] = s; ssq[t][r] = sq;
        }
    }
    // reduce over the 16 lanes of each quad (cols within this wave)
#pragma unroll
    for (int m = 1; m <= 8; m <<= 1) {
#pragma unroll
        for (int t = 0; t < 4; t++)
#pragma unroll
            for (int r = 0; r < 4; r++) {
                ssum[t][r] += __shfl_xor(ssum[t][r], m);
                ssq[t][r] += __shfl_xor(ssq[t][r], m);
            }
    }
    // cross-wave reduction via LDS (reuse As region)
    float* Ls = (float*)As;          // [64][4]
    float* Lq = Ls + 256;            // [64][4]
    if (l15 == 0) {
#pragma unroll
        for (int t = 0; t < 4; t++)
#pragma unroll
            for (int r = 0; r < 4; r++) {
                int lr = t * 16 + q * 4 + r;
                Ls[lr * 4 + w] = ssum[t][r];
                Lq[lr * 4 + w] = ssq[t][r];
            }
    }
    __syncthreads();

#pragma unroll
    for (int t = 0; t < 4; t++) {
#pragma unroll
        for (int r = 0; r < 4; r++) {
            int lr = t * 16 + q * 4 + r;
            int gm = m0 + lr;
            float tot = Ls[lr * 4 + 0] + Ls[lr * 4 + 1] + Ls[lr * 4 + 2] + Ls[lr * 4 + 3];
            float totq = Lq[lr * 4 + 0] + Lq[lr * 4 + 1] + Lq[lr * 4 + 2] + Lq[lr * 4 + 3];
            float mean = tot * (1.f / DD);
            float var = totq * (1.f / DD) - mean * mean;
            float rs = rsqrtf(var + EPSLN);
            if (gm < M) {
#pragma unroll
                for (int u = 0; u < 4; u++) {
                    int gn = wn + u * 16 + l15;
                    float o = (x[t][r][u] - mean) * rs * gg[u] + bb[u];
                    if (sizeof(OT) == 2)
                        ((unsigned short*)out)[(size_t)gm * DD + gn] = f2bf(o);
                    else
                        ((float*)out)[(size_t)gm * DD + gn] = o;
                }
            }
        }
    }
}

// ---------------------------------------------------------------------------
// Fused FFN (DIAGNOSTIC: compiled but NOT launched this round).
// Rounds 1-2 failed at container level with this kernel launched; keeping it
// compiled-only splits "compile hang" from "runtime wedge" vs "infra".
// ---------------------------------------------------------------------------
__launch_bounds__(256)
__global__ void ffn_k(const unsigned short* __restrict__ A,     // qbf [MPAD][256], rows>=M are zero
                      const unsigned short* __restrict__ Wt1,   // [1024][256]
                      const float* __restrict__ b1,
                      const unsigned short* __restrict__ Wt2,   // [256][1024]
                      const float* __restrict__ b2,
                      const float* __restrict__ g, const float* __restrict__ be,
                      float* __restrict__ out, int M) {
    __shared__ __align__(16) unsigned short qs[8 * 64 * 32];   // 32 KB: [kk][row][k8]
    __shared__ __align__(16) unsigned short Hs[64 * 128];      // 16 KB, swizzled

    const int tid = threadIdx.x;
    const int m0 = blockIdx.x * 64;
    const int w = tid >> 6, lane = tid & 63;
    const int q = lane >> 4, l15 = lane & 15;
    const int wn1 = w * 32;   // GEMM1: this wave's 32 hid cols within the 128-chunk
    const int wn2 = w * 64;   // GEMM2: this wave's 64 output cols

    // stage q tile once: 8 passes, k-blocked layout so gld16 dest is linear
    {
        const int sr = tid >> 2;
        const int sk = (tid & 3) * 8;
        const unsigned short* Ag = A + (size_t)(m0 + sr) * 256 + sk;
        char* qsB = (char*)qs;
#pragma unroll
        for (int p = 0; p < 8; p++)
            gld16(Ag + p * 32, qsB + p * 4096 + tid * 16);
    }

    floatx4 acc2[4][4];
#pragma unroll
    for (int t = 0; t < 4; t++)
#pragma unroll
        for (int u = 0; u < 4; u++) {
            floatx4 z = {0.f, 0.f, 0.f, 0.f};
            acc2[t][u] = z;
        }

    __syncthreads();   // qs ready

#pragma unroll 1
    for (int j = 0; j < 8; j++) {
        // ---- GEMM1: H[64][128-chunk j] = q @ W1chunk (K=256) ----
        floatx4 acc1[4][2];
#pragma unroll
        for (int t = 0; t < 4; t++)
#pragma unroll
            for (int u2 = 0; u2 < 2; u2++) {
                floatx4 z = {0.f, 0.f, 0.f, 0.f};
                acc1[t][u2] = z;
            }
        const unsigned short* W1p = Wt1 + (size_t)(j * 128 + wn1) * 256;
#pragma unroll
        for (int kk = 0; kk < 8; kk++) {
            bf16x8 af[4], bf1[2];
#pragma unroll
            for (int t = 0; t < 4; t++)
                af[t] = *reinterpret_cast<const bf16x8*>(&qs[kk * 2048 + (t * 16 + l15) * 32 + q * 8]);
#pragma unroll
            for (int u2 = 0; u2 < 2; u2++)
                bf1[u2] = *reinterpret_cast<const bf16x8*>(&W1p[(size_t)(u2 * 16 + l15) * 256 + kk * 32 + q * 8]);
#pragma unroll
            for (int t = 0; t < 4; t++)
#pragma unroll
                for (int u2 = 0; u2 < 2; u2++)
                    acc1[t][u2] = __builtin_amdgcn_mfma_f32_16x16x32_bf16(af[t], bf1[u2], acc1[t][u2], 0, 0, 0);
        }
        __syncthreads();   // prev chunk's GEMM2 Hs reads complete
        // ---- bias + exact GELU -> Hs (swizzled) ----
#pragma unroll
        for (int u2 = 0; u2 < 2; u2++) {
            int col = wn1 + u2 * 16 + l15;
            float bv = b1[j * 128 + col];
#pragma unroll
            for (int t = 0; t < 4; t++)
#pragma unroll
                for (int r = 0; r < 4; r++) {
                    int row = t * 16 + q * 4 + r;
                    float v = acc1[t][u2][r] + bv;
                    v = 0.5f * v * (1.f + erff(v * 0.70710678118f));
                    int bo = (row * 256 + col * 2) ^ ((row & 7) << 4);
                    *(unsigned short*)((char*)Hs + bo) = f2bf(v);
                }
        }
        __syncthreads();   // Hs ready
        // ---- GEMM2: acc2 += Hchunk @ W2chunk (K=128) ----
        const unsigned short* W2p = Wt2 + (size_t)wn2 * 1024 + j * 128;
#pragma unroll
        for (int kk2 = 0; kk2 < 4; kk2++) {
            bf16x8 af2[4], bf2[4];
#pragma unroll
            for (int t = 0; t < 4; t++) {
                int row = t * 16 + l15;
                int bo = (row * 256 + (kk2 * 32 + q * 8) * 2) ^ ((row & 7) << 4);
                af2[t] = *reinterpret_cast<const bf16x8*>((const char*)Hs + bo);
            }
#pragma unroll
            for (int u = 0; u < 4; u++)
                bf2[u] = *reinterpret_cast<const bf16x8*>(&W2p[(size_t)(u * 16 + l15) * 1024 + kk2 * 32 + q * 8]);
#pragma unroll
            for (int t = 0; t < 4; t++)
#pragma unroll
                for (int u = 0; u < 4; u++)
                    acc2[t][u] = __builtin_amdgcn_mfma_f32_16x16x32_bf16(af2[t], bf2[u], acc2[t][u], 0, 0, 0);
        }
    }

    // ---- epilogue: + b2 + residual(q, read from LDS qs) + LN2 -> out f32 ----
    float gg[4], bb[4], bias_v[4];
#pragma unroll
    for (int u = 0; u < 4; u++) {
        int gn = wn2 + u * 16 + l15;
        gg[u] = g[gn]; bb[u] = be[gn]; bias_v[u] = b2[gn];
    }

    float x[4][4][4];     // [t][r][u]
    float ssum[4][4], ssq[4][4];
#pragma unroll
    for (int t = 0; t < 4; t++) {
#pragma unroll
        for (int r = 0; r < 4; r++) {
            int row = t * 16 + q * 4 + r;
            float s = 0.f, sq = 0.f;
#pragma unroll
            for (int u = 0; u < 4; u++) {
                int gn = wn2 + u * 16 + l15;
                float rv = bf2f(qs[(gn >> 5) * 2048 + row * 32 + (gn & 31)]);
                float xx = acc2[t][u][r] + bias_v[u] + rv;
                x[t][r][u] = xx;
                s += xx; sq += xx * xx;
            }
            ssum[t][r] = s; ssq[t][r] = sq;
        }
    }
#pragma unroll
    for (int m = 1; m <= 8; m <<= 1) {
#pragma unroll
        for (int t = 0; t < 4; t++)
#pragma unroll
            for (int r = 0; r < 4; r++) {
                ssum[t][r] += __shfl_xor(ssum[t][r], m);
                ssq[t][r] += __shfl_xor(ssq[t][r], m);
            }
    }
    __syncthreads();   // all qs residual reads + Hs GEMM2 reads done
    float* Ls = (float*)qs;          // [64][4]
    float* Lq = Ls + 256;            // [64][4]
    if (l15 == 0) {
#pragma unroll
        for (int t = 0; t < 4; t++)
#pragma unroll
            for (int r = 0; r < 4; r++) {
                int lr = t * 16 + q * 4 + r;
                Ls[lr * 4 + w] = ssum[t][r];
                Lq[lr * 4 + w] = ssq[t][r];
            }
    }
    __syncthreads();

#pragma unroll
    for (int t = 0; t < 4; t++) {
#pragma unroll
        for (int r = 0; r < 4; r++) {
            int lr = t * 16 + q * 4 + r;
            int gm = m0 + lr;
            float tot = Ls[lr * 4 + 0] + Ls[lr * 4 + 1] + Ls[lr * 4 + 2] + Ls[lr * 4 + 3];
            float totq = Lq[lr * 4 + 0] + Lq[lr * 4 + 1] + Lq[lr * 4 + 2] + Lq[lr * 4 + 3];
            float mean = tot * (1.f / DD);
            float var = totq * (1.f / DD) - mean * mean;
            float rs = rsqrtf(var + EPSLN);
            if (gm < M) {
#pragma unroll
                for (int u = 0; u < 4; u++) {
                    int gn = wn2 + u * 16 + l15;
                    out[(size_t)gm * DD + gn] = (x[t][r][u] - mean) * rs * gg[u] + bb[u];
                }
            }
        }
    }
}

// ---------------------------------------------------------------------------
// Activation casts fused: query -> qbf [52736x256], p3/p4/p5 -> featsb.
// ---------------------------------------------------------------------------
#define QELEMS   13500416   // 52736*256
#define F3ELEMS  10256384   // 40064*256
#define F4ELEMS   2588672   // 10112*256
#define TOTELEMS 27000832

__launch_bounds__(256)
__global__ void cast_acts_k(const float* __restrict__ query, const float* __restrict__ p3,
                            const float* __restrict__ p4, const float* __restrict__ p5,
                            unsigned short* __restrict__ qbf, unsigned short* __restrict__ featsb) {
    int idx4 = (blockIdx.x * 256 + threadIdx.x) * 4;
    if (idx4 >= TOTELEMS) return;
    const float* src; unsigned short* dst; int local, real;
    if (idx4 < QELEMS) {
        src = query; dst = qbf; local = idx4; real = 13440000;
    } else {
        int j = idx4 - QELEMS;
        if (j < F3ELEMS)              { src = p3; dst = featsb;                    local = j;            real = 10240000; }
        else if (j < F3ELEMS + F4ELEMS){ src = p4; dst = featsb + F3ELEMS;         local = j - F3ELEMS;  real = 2560000; }
        else                          { src = p5; dst = featsb + F3ELEMS + F4ELEMS; local = j - F3ELEMS - F4ELEMS; real = 640000; }
    }
    float4 v = make_float4(0.f, 0.f, 0.f, 0.f);
    if (local < real) v = *(const float4*)&src[local];
    ushort4 o;
    o.x = f2bf(v.x); o.y = f2bf(v.y); o.z = f2bf(v.z); o.w = f2bf(v.w);
    *(ushort4*)&dst[local] = o;
}

// ---------------------------------------------------------------------------
// Weight preps: Wtq [384][256] (Woff|Wattn|Wref|0), Wtv, Wto, Wt1, Wt2,
// then biasq[384] f32 (boff|battn|bref|0).
// ---------------------------------------------------------------------------
#define WTQ_E   98304
#define WTV_E   (WTQ_E + 65536)     // 163840
#define WTO_E   (WTV_E + 65536)     // 229376
#define WT1_E   (WTO_E + 262144)    // 491520
#define WT2_E   (WT1_E + 262144)    // 753664
#define PREP_TOT (WT2_E + 384)

__launch_bounds__(256)
__global__ void prep_w_k(const float* __restrict__ Woff, const float* __restrict__ Wattn,
                         const float* __restrict__ Wref, const float* __restrict__ Wv,
                         const float* __restrict__ Wo, const float* __restrict__ W1,
                         const float* __restrict__ W2, const float* __restrict__ boff,
                         const float* __restrict__ battn, const float* __restrict__ bref,
                         unsigned short* __restrict__ warena, float* __restrict__ biasq) {
    int i = blockIdx.x * 256 + threadIdx.x;
    if (i >= PREP_TOT) return;
    if (i >= WT2_E) {
        int t = i - WT2_E;
        biasq[t] = (t < 192) ? boff[t] : (t < 288 ? battn[t - 192] : (t < 290 ? bref[t - 288] : 0.f));
        return;
    }
    float v;
    if (i < WTQ_E) {
        int n = i >> 8, k = i & 255;
        v = (n < 192) ? Woff[k * 192 + n]
          : (n < 288) ? Wattn[k * 96 + (n - 192)]
          : (n < 290) ? Wref[k * 2 + (n - 288)] : 0.f;
    } else if (i < WTV_E) {
        int j = i - WTQ_E; int n = j >> 8, k = j & 255;
        v = Wv[k * 256 + n];
    } else if (i < WTO_E) {
        int j = i - WTV_E; int n = j >> 8, k = j & 255;
        v = Wo[k * 256 + n];
    } else if (i < WT1_E) {
        int j = i - WTO_E; int n = j >> 8, k = j & 255;
        v = W1[k * 1024 + n];
    } else {
        int j = i - WT1_E; int n = j >> 10, k = j & 1023;
        v = W2[k * 256 + n];
    }
    warena[i] = f2bf(v);
}

// ---------------------------------------------------------------------------
// softmax over groups of 12 from projb (ldc 320, offset 192) -> bf16 aw.
// ---------------------------------------------------------------------------
__launch_bounds__(256)
__global__ void softmax12_k(const float* __restrict__ projb, unsigned short* __restrict__ aw) {
    int rh = blockIdx.x * 256 + threadIdx.x;
    if (rh >= MROWS * NHH) return;
    int bn = rh >> 3, h = rh & 7;
    const float* p = projb + (size_t)bn * 320 + 192 + h * 12;
    float v[12], mx = -1e30f;
#pragma unroll
    for (int i = 0; i < 12; i++) { v[i] = p[i]; mx = fmaxf(mx, v[i]); }
    float s = 0.f;
#pragma unroll
    for (int i = 0; i < 12; i++) { v[i] = expf(v[i] - mx); s += v[i]; }
    float inv = 1.f / s;
    unsigned short* o = aw + (size_t)rh * 12;
#pragma unroll
    for (int i = 0; i < 12; i++) o[i] = f2bf(v[i] * inv);
}

// ---------------------------------------------------------------------------
// Deformable sampling v4: 128 threads = 2 waves, one (b,n) per wave.
// Ref logits read from projb cols 288/289 (sigmoid here). Packed LDS
// {weight, byte-offset} pairs -> one ds_read_b64 per corner.
// ---------------------------------------------------------------------------
__launch_bounds__(128)
__global__ void sample_k(const unsigned short* __restrict__ val, const float* __restrict__ projb,
                         const unsigned short* __restrict__ aw,
                         unsigned short* __restrict__ out) {
    const int wv = threadIdx.x >> 6;
    const int lane = threadIdx.x & 63;
    const int bn = blockIdx.x * 2 + wv;
    const int b = bn / NTOT;
    __shared__ uint2 sc[2][96][4];

    const float* prow = projb + (size_t)bn * 320;
    float rx = 1.f / (1.f + expf(-prow[288]));
    float ry = 1.f / (1.f + expf(-prow[289]));
    for (int s0 = lane; s0 < 96; s0 += 64) {
        const int lp = s0 % 12;
        const int l = lp >> 2;
        int Hl, Wl, loff;
        if (l == 0)      { Hl = 100; Wl = 100; loff = 0; }
        else if (l == 1) { Hl = 50;  Wl = 50;  loff = 10000; }
        else             { Hl = 25;  Wl = 25;  loff = 12500; }
        float ox = prow[s0 * 2 + 0];
        float oy = prow[s0 * 2 + 1];
        float a  = bf2f(aw[(size_t)bn * 96 + s0]);
        float x = rx * (float)Wl + ox - 0.5f;
        float y = ry * (float)Hl + oy - 0.5f;
        x = fminf(fmaxf(x, -1e4f), 1e4f);
        y = fminf(fmaxf(y, -1e4f), 1e4f);
        float x0f = floorf(x), y0f = floorf(y);
        float lx = x - x0f, ly = y - y0f;
        int x0 = (int)x0f, y0 = (int)y0f;
#pragma unroll
        for (int c = 0; c < 4; c++) {
            int xi = x0 + (c & 1);
            int yi = y0 + (c >> 1);
            bool ok = (xi >= 0) && (xi < Wl) && (yi >= 0) && (yi < Hl);
            int xc = min(max(xi, 0), Wl - 1);
            int yc = min(max(yi, 0), Hl - 1);
            int idx = b * NTOT + loff + yc * Wl + xc;
            float wgt = ((c & 1) ? lx : 1.f - lx) * ((c >> 1) ? ly : 1.f - ly);
            sc[wv][s0][c] = make_uint2(__float_as_uint(ok ? a * wgt : 0.f), (unsigned)(idx * 512));
        }
    }
    __syncthreads();

    const int h = lane >> 3;
    const int dq = (lane & 7) * 4;
    const char* vb = (const char*)val + h * 64 + dq * 2;
    float a0 = 0.f, a1 = 0.f, a2 = 0.f, a3 = 0.f;
#pragma unroll
    for (int lp = 0; lp < 12; lp++) {
        int s = h * 12 + lp;
#pragma unroll
        for (int c = 0; c < 4; c++) {
            uint2 p = sc[wv][s][c];
            float wgt = __uint_as_float(p.x);
            uint2 u = *(const uint2*)(vb + p.y);
            a0 += wgt * __uint_as_float(u.x << 16);
            a1 += wgt * __uint_as_float(u.x & 0xFFFF0000u);
            a2 += wgt * __uint_as_float(u.y << 16);
            a3 += wgt * __uint_as_float(u.y & 0xFFFF0000u);
        }
    }
    uint2 ov;
    ov.x = (unsigned)f2bf(a0) | ((unsigned)f2bf(a1) << 16);
    ov.y = (unsigned)f2bf(a2) | ((unsigned)f2bf(a3) << 16);
    *(uint2*)(out + (size_t)bn * DD + h * 32 + dq) = ov;
}

// ---------------------------------------------------------------------------
extern "C" void kernel_launch(void* const* d_in, const int* in_sizes, int n_in,
                              void* d_out, int out_size, void* d_ws, size_t ws_size,
                              hipStream_t stream) {
    const float* query = (const float*)d_in[0];
    const float* p3    = (const float*)d_in[1];
    const float* p4    = (const float*)d_in[2];
    const float* p5    = (const float*)d_in[3];
    const float* Wv    = (const float*)d_in[4];
    const float* bv    = (const float*)d_in[5];
    const float* Woff  = (const float*)d_in[6];
    const float* boff  = (const float*)d_in[7];
    const float* Wattn = (const float*)d_in[8];
    const float* battn = (const float*)d_in[9];
    const float* Wref  = (const float*)d_in[10];
    const float* bref  = (const float*)d_in[11];
    const float* Wo    = (const float*)d_in[12];
    const float* bo    = (const float*)d_in[13];
    const float* W1    = (const float*)d_in[14];
    const float* b1    = (const float*)d_in[15];
    const float* W2    = (const float*)d_in[16];
    const float* b2    = (const float*)d_in[17];
    const float* g1    = (const float*)d_in[18];
    const float* be1   = (const float*)d_in[19];
    const float* g2    = (const float*)d_in[20];
    const float* be2   = (const float*)d_in[21];
    float* outp = (float*)d_out;

    // ---- workspace layout (bytes), total ~186.9 MB ----
    char* wsb = (char*)d_ws;
    unsigned short* qbf    = (unsigned short*)(wsb + 0);           // 52736x256 bf16  [0, 27000832)
    float*          projb  = (float*)(wsb + 27000832);             // 52736x320 f32   [.., 94502912)
    unsigned short* awb    = (unsigned short*)(wsb + 94502912);    // 52500x96 bf16   [.., 104582912)
    unsigned short* featsb = (unsigned short*)(wsb + 104582912);   // 52736x256 bf16  [.., 131583744)
    unsigned short* valb   = (unsigned short*)(wsb + 131583744);   // 52500x256 bf16  [.., 158463744)
    unsigned short* sampb  = (unsigned short*)(wsb + 158463744);   // 52608x256 bf16  [.., 185399296)
    unsigned short* warena = (unsigned short*)(wsb + 185399296);   // 753664 bf16     [.., 186906624)
    float*          biasq  = (float*)(wsb + 186906624);            // 384 f32
    // hid aliases projb+awb+featsb+valb (all dead by W1 time): 108.0 MB needed,
    // region [27000832, 158463744) = 131.5 MB available.
    unsigned short* hidb   = (unsigned short*)(wsb + 27000832);    // 52736x1024 bf16

    unsigned short* Wtq = warena;                 // [384][256]
    unsigned short* Wtv = warena + WTQ_E;
    unsigned short* Wto = warena + WTV_E;
    unsigned short* Wt1 = warena + WTO_E;         // [1024][256]
    unsigned short* Wt2 = warena + WT1_E;         // [256][1024]

    // 1) activation casts
    cast_acts_k<<<dim3(TOTELEMS / 4 / 256), 256, 0, stream>>>(query, p3, p4, p5, qbf, featsb);
    // 2) weight preps (incl. Wref/bref folded into q-proj weight)
    prep_w_k<<<dim3((PREP_TOT + 255) / 256), 256, 0, stream>>>(
        Woff, Wattn, Wref, Wv, Wo, W1, W2, boff, battn, bref, warena, biasq);
    // 3) combined q projection: [off | attn logits | ref logits] -> projb [.,320]
    mm_k<EPI_F32, float><<<dim3(MPAD / 128, 3), 256, 0, stream>>>(
        qbf, Wtq, biasq, projb, MROWS, 256, 290, 320, 0);
    // 4) softmax -> aw bf16
    softmax12_k<<<dim3((MROWS * NHH + 255) / 256), 256, 0, stream>>>(projb, awb);
    // 5) value projection (single dispatch, per-row segment remap)
    mm_k<EPI_VALSEG, unsigned short><<<dim3(MPAD / 128, 2), 256, 0, stream>>>(
        featsb, Wtv, bv, valb, 0, 256, 256, 256, 0);
    // 6) deformable sampling (2 query points per block)
    sample_k<<<dim3(MROWS / 2), 128, 0, stream>>>(valb, projb, awb, sampb);
    // 7) Wo + residual(query f32) + LN1 -> qbf
    gemmln_k<float, unsigned short><<<dim3((MROWS + 63) / 64), 256, 0, stream>>>(
        sampb, Wto, bo, query, g1, be1, qbf, MROWS, 256);
    // 8) W1 + GELU -> hid (pad rows zeroed up to 52736)
    mm_k<EPI_GELU, unsigned short><<<dim3(MPAD / 128, FFD / 128), 256, 0, stream>>>(
        qbf, Wt1, b1, hidb, MROWS, 256, FFD, FFD, MPAD);
    // 9) W2 + residual(qbf bf16) + LN2 -> out f32
    gemmln_k<unsigned short, float><<<dim3((MROWS + 63) / 64), 256, 0, stream>>>(
        hidb, Wt2, b2, qbf, g2, be2, outp, MROWS, 1024);
}

// Round 4
// 565.118 us; speedup vs baseline: 1.0592x; 1.0538x over previous
//
#include <hip/hip_runtime.h>
#include <math.h>

// Problem constants
#define BQ    4
#define NTOT  13125
#define DD    256
#define NHH   8
#define FFD   1024
#define EPSLN 1e-5f
#define MROWS (BQ * NTOT)        // 52500
#define MPAD  52736              // 412*128

typedef __bf16 bf16_t;
typedef bf16_t bf16x8 __attribute__((ext_vector_type(8)));
typedef float floatx4 __attribute__((ext_vector_type(4)));

__device__ __forceinline__ unsigned short f2bf(float f) {
    unsigned u = __float_as_uint(f);
    return (unsigned short)((u + 0x7FFFu + ((u >> 16) & 1u)) >> 16);
}
__device__ __forceinline__ float bf2f(unsigned short h) {
    return __uint_as_float(((unsigned)h) << 16);
}

typedef const __attribute__((address_space(1))) unsigned int* gptr_t;
typedef __attribute__((address_space(3))) unsigned int* lptr_t;
__device__ __forceinline__ void gld16(const void* g, void* l) {
    __builtin_amdgcn_global_load_lds((gptr_t)g, (lptr_t)l, 16, 0, 0);
}

enum { EPI_F32 = 0, EPI_GELU = 2, EPI_VALSEG = 3 };

// Map padded concatenated feature row -> value-buffer row (b*NTOT + loff + nl)
__device__ __forceinline__ int val_row(int gm) {
    if (gm < 40064) {
        if (gm >= 40000) return -1;
        int b = gm / 10000; int nl = gm - b * 10000;
        return b * NTOT + nl;
    } else if (gm < 50176) {
        int r = gm - 40064;
        if (r >= 10000) return -1;
        int b = r / 2500; int nl = r - b * 2500;
        return b * NTOT + 10000 + nl;
    } else {
        int r = gm - 50176;
        if (r >= 2500) return -1;
        int b = r / 625; int nl = r - b * 625;
        return b * NTOT + 12500 + nl;
    }
}

// ---------------------------------------------------------------------------
// bf16 MFMA GEMM (m97 structure): A [Mpad,K] bf16, Bt [Npad,K] bf16.
// 128x128 tile, BK=32, 4 waves, 4x4 grid of 16x16x32 mfma.
// ---------------------------------------------------------------------------
template <int EPI, typename OutT>
__launch_bounds__(256)
__global__ void mm_k(const unsigned short* __restrict__ A,
                     const unsigned short* __restrict__ Bt,
                     const float* __restrict__ bias, OutT* __restrict__ C,
                     int M, int K, int Nout, int ldc, int Mstore) {
    __shared__ __align__(16) unsigned short As[128 * 32];
    __shared__ __align__(16) unsigned short Bs[128 * 32];

    const int tid = threadIdx.x;
    const int m0 = blockIdx.x * 128;
    const int n0 = blockIdx.y * 128;
    const int w = tid >> 6, lane = tid & 63;
    const int q = lane >> 4, l15 = lane & 15;
    const int wm = (w & 1) * 64, wn = (w >> 1) * 64;

    const int sr = tid >> 2;
    const int sk = (tid & 3) * 8;

    const unsigned short* Ag = A + (size_t)(m0 + sr) * K + sk;
    const unsigned short* Bg = Bt + (size_t)(n0 + sr) * K + sk;
    char* AsB = (char*)As;
    char* BsB = (char*)Bs;

    floatx4 acc[4][4];
#pragma unroll
    for (int t = 0; t < 4; t++)
#pragma unroll
        for (int u = 0; u < 4; u++) {
            floatx4 z = {0.f, 0.f, 0.f, 0.f};
            acc[t][u] = z;
        }

    for (int k0 = 0; k0 < K; k0 += 32) {
        gld16(Ag + k0, AsB + tid * 16);
        gld16(Ag + (size_t)64 * K + k0, AsB + 4096 + tid * 16);
        gld16(Bg + k0, BsB + tid * 16);
        gld16(Bg + (size_t)64 * K + k0, BsB + 4096 + tid * 16);
        __syncthreads();

        bf16x8 af[4], bfr[4];
#pragma unroll
        for (int t = 0; t < 4; t++)
            af[t] = *reinterpret_cast<const bf16x8*>(&As[(wm + t * 16 + l15) * 32 + q * 8]);
#pragma unroll
        for (int u = 0; u < 4; u++)
            bfr[u] = *reinterpret_cast<const bf16x8*>(&Bs[(wn + u * 16 + l15) * 32 + q * 8]);
#pragma unroll
        for (int t = 0; t < 4; t++)
#pragma unroll
            for (int u = 0; u < 4; u++)
                acc[t][u] = __builtin_amdgcn_mfma_f32_16x16x32_bf16(af[t], bfr[u], acc[t][u], 0, 0, 0);
        __syncthreads();
    }

    float bias_v[4];
#pragma unroll
    for (int u = 0; u < 4; u++) {
        int gn = n0 + wn + u * 16 + l15;
        bias_v[u] = (gn < Nout) ? bias[gn] : 0.f;
    }

#pragma unroll
    for (int t = 0; t < 4; t++) {
#pragma unroll
        for (int r = 0; r < 4; r++) {
            int gm = m0 + wm + t * 16 + q * 4 + r;
            int orow = gm;
            if (EPI == EPI_VALSEG) orow = val_row(gm);
#pragma unroll
            for (int u = 0; u < 4; u++) {
                int gn = n0 + wn + u * 16 + l15;
                if (gn >= Nout) continue;
                float v = acc[t][u][r] + bias_v[u];
                if (EPI == EPI_GELU) {
                    v = 0.5f * v * (1.f + erff(v * 0.70710678118f));
                    if (gm < Mstore) {
                        float ov = (gm < M) ? v : 0.f;
                        ((unsigned short*)C)[(size_t)gm * ldc + gn] = f2bf(ov);
                    }
                } else if (EPI == EPI_VALSEG) {
                    if (orow >= 0)
                        ((unsigned short*)C)[(size_t)orow * ldc + gn] = f2bf(v);
                } else {
                    if (gm < M) ((float*)C)[(size_t)gm * ldc + gn] = v;
                }
            }
        }
    }
}

// ---------------------------------------------------------------------------
// Fused GEMM (N=256) + bias + residual + LayerNorm.
// Tile 64 rows x 256 cols (full row), 4 waves col-split 64 each.
// RT: residual dtype (float or ushort/bf16); OT: output (ushort/bf16 or float).
// ---------------------------------------------------------------------------
template <typename RT, typename OT>
__launch_bounds__(256)
__global__ void gemmln_k(const unsigned short* __restrict__ A,
                         const unsigned short* __restrict__ Bt,
                         const float* __restrict__ bias, const RT* __restrict__ res,
                         const float* __restrict__ g, const float* __restrict__ be,
                         OT* __restrict__ out, int M, int K) {
    __shared__ __align__(16) unsigned short As[64 * 32];    // 4 KB
    __shared__ __align__(16) unsigned short Bs[256 * 32];   // 16 KB

    const int tid = threadIdx.x;
    const int m0 = blockIdx.x * 64;
    const int w = tid >> 6, lane = tid & 63;
    const int q = lane >> 4, l15 = lane & 15;
    const int wn = w * 64;

    const int sr = tid >> 2;
    const int sk = (tid & 3) * 8;
    const unsigned short* Ag = A + (size_t)(m0 + sr) * K + sk;
    const unsigned short* Bg = Bt + (size_t)sr * K + sk;
    char* AsB = (char*)As;
    char* BsB = (char*)Bs;

    floatx4 acc[4][4];
#pragma unroll
    for (int t = 0; t < 4; t++)
#pragma unroll
        for (int u = 0; u < 4; u++) {
            floatx4 z = {0.f, 0.f, 0.f, 0.f};
            acc[t][u] = z;
        }

    for (int k0 = 0; k0 < K; k0 += 32) {
        gld16(Ag + k0, AsB + tid * 16);
#pragma unroll
        for (int j = 0; j < 4; j++)
            gld16(Bg + (size_t)j * 64 * K + k0, BsB + j * 4096 + tid * 16);
        __syncthreads();

        bf16x8 af[4], bfr[4];
#pragma unroll
        for (int t = 0; t < 4; t++)
            af[t] = *reinterpret_cast<const bf16x8*>(&As[(t * 16 + l15) * 32 + q * 8]);
#pragma unroll
        for (int u = 0; u < 4; u++)
            bfr[u] = *reinterpret_cast<const bf16x8*>(&Bs[(wn + u * 16 + l15) * 32 + q * 8]);
#pragma unroll
        for (int t = 0; t < 4; t++)
#pragma unroll
            for (int u = 0; u < 4; u++)
                acc[t][u] = __builtin_amdgcn_mfma_f32_16x16x32_bf16(af[t], bfr[u], acc[t][u], 0, 0, 0);
        __syncthreads();
    }
    // after final sync: all LDS frag reads done; reuse As for row stats.

    float gg[4], bb[4], bias_v[4];
#pragma unroll
    for (int u = 0; u < 4; u++) {
        int gn = wn + u * 16 + l15;
        gg[u] = g[gn]; bb[u] = be[gn]; bias_v[u] = bias[gn];
    }

    float x[4][4][4];     // [t][r][u]
    float ssum[4][4], ssq[4][4];
#pragma unroll
    for (int t = 0; t < 4; t++) {
#pragma unroll
        for (int r = 0; r < 4; r++) {
            int gm = m0 + t * 16 + q * 4 + r;
            bool valid = gm < M;
            float s = 0.f, sq = 0.f;
#pragma unroll
            for (int u = 0; u < 4; u++) {
                int gn = wn + u * 16 + l15;
                float rv = 0.f;
                if (valid) {
                    if (sizeof(RT) == 2)
                        rv = bf2f(((const unsigned short*)res)[(size_t)gm * DD + gn]);
                    else
                        rv = ((const float*)res)[(size_t)gm * DD + gn];
                }
                float xx = acc[t][u][r] + bias_v[u] + rv;
                x[t][r][u] = xx;
                s += xx; sq += xx * xx;
            }
            ssum[t][r] = s; ssq[t][r] = sq;
        }
    }
    // reduce over the 16 lanes of each quad (cols within this wave)
#pragma unroll
    for (int m = 1; m <= 8; m <<= 1) {
#pragma unroll
        for (int t = 0; t < 4; t++)
#pragma unroll
            for (int r = 0; r < 4; r++) {
                ssum[t][r] += __shfl_xor(ssum[t][r], m);
                ssq[t][r] += __shfl_xor(ssq[t][r], m);
            }
    }
    // cross-wave reduction via LDS (reuse As region)
    float* Ls = (float*)As;          // [64][4]
    float* Lq = Ls + 256;            // [64][4]
    if (l15 == 0) {
#pragma unroll
        for (int t = 0; t < 4; t++)
#pragma unroll
            for (int r = 0; r < 4; r++) {
                int lr = t * 16 + q * 4 + r;
                Ls[lr * 4 + w] = ssum[t][r];
                Lq[lr * 4 + w] = ssq[t][r];
            }
    }
    __syncthreads();

#pragma unroll
    for (int t = 0; t < 4; t++) {
#pragma unroll
        for (int r = 0; r < 4; r++) {
            int lr = t * 16 + q * 4 + r;
            int gm = m0 + lr;
            float tot = Ls[lr * 4 + 0] + Ls[lr * 4 + 1] + Ls[lr * 4 + 2] + Ls[lr * 4 + 3];
            float totq = Lq[lr * 4 + 0] + Lq[lr * 4 + 1] + Lq[lr * 4 + 2] + Lq[lr * 4 + 3];
            float mean = tot * (1.f / DD);
            float var = totq * (1.f / DD) - mean * mean;
            float rs = rsqrtf(var + EPSLN);
            if (gm < M) {
#pragma unroll
                for (int u = 0; u < 4; u++) {
                    int gn = wn + u * 16 + l15;
                    float o = (x[t][r][u] - mean) * rs * gg[u] + bb[u];
                    if (sizeof(OT) == 2)
                        ((unsigned short*)out)[(size_t)gm * DD + gn] = f2bf(o);
                    else
                        ((float*)out)[(size_t)gm * DD + gn] = o;
                }
            }
        }
    }
}

// ---------------------------------------------------------------------------
// Fused FFN: out = LN2( q + gelu(q@W1+b1)@W2 + b2 ), per 64-row block.
// hid chunk (64x128) never leaves the CU: GEMM1 -> GELU -> LDS -> GEMM2.
// B-operand fragments are read DIRECTLY from global (weights are L2-resident,
// 1 MB total) -> no B staging, only 2 barriers per 128-col hid chunk.
// Hs is XOR-swizzled (byte ^= (row&7)<<4) so the stride-256B A-fragment
// reads are bank-conflict-free (G4).
// ---------------------------------------------------------------------------
__launch_bounds__(256)
__global__ void ffn_k(const unsigned short* __restrict__ A,     // qbf [MPAD][256], rows>=M are zero
                      const unsigned short* __restrict__ Wt1,   // [1024][256]
                      const float* __restrict__ b1,
                      const unsigned short* __restrict__ Wt2,   // [256][1024]
                      const float* __restrict__ b2,
                      const float* __restrict__ g, const float* __restrict__ be,
                      float* __restrict__ out, int M) {
    __shared__ __align__(16) unsigned short qs[8 * 64 * 32];   // 32 KB: [kk][row][k8]
    __shared__ __align__(16) unsigned short Hs[64 * 128];      // 16 KB, swizzled

    const int tid = threadIdx.x;
    const int m0 = blockIdx.x * 64;
    const int w = tid >> 6, lane = tid & 63;
    const int q = lane >> 4, l15 = lane & 15;
    const int wn1 = w * 32;   // GEMM1: this wave's 32 hid cols within the 128-chunk
    const int wn2 = w * 64;   // GEMM2: this wave's 64 output cols

    // stage q tile once: 8 passes, k-blocked layout so gld16 dest is linear
    {
        const int sr = tid >> 2;
        const int sk = (tid & 3) * 8;
        const unsigned short* Ag = A + (size_t)(m0 + sr) * 256 + sk;
        char* qsB = (char*)qs;
#pragma unroll
        for (int p = 0; p < 8; p++)
            gld16(Ag + p * 32, qsB + p * 4096 + tid * 16);
    }

    floatx4 acc2[4][4];
#pragma unroll
    for (int t = 0; t < 4; t++)
#pragma unroll
        for (int u = 0; u < 4; u++) {
            floatx4 z = {0.f, 0.f, 0.f, 0.f};
            acc2[t][u] = z;
        }

    __syncthreads();   // qs ready

#pragma unroll 1
    for (int j = 0; j < 8; j++) {
        // ---- GEMM1: H[64][128-chunk j] = q @ W1chunk (K=256) ----
        floatx4 acc1[4][2];
#pragma unroll
        for (int t = 0; t < 4; t++)
#pragma unroll
            for (int u2 = 0; u2 < 2; u2++) {
                floatx4 z = {0.f, 0.f, 0.f, 0.f};
                acc1[t][u2] = z;
            }
        const unsigned short* W1p = Wt1 + (size_t)(j * 128 + wn1) * 256;
#pragma unroll
        for (int kk = 0; kk < 8; kk++) {
            bf16x8 af[4], bf1[2];
#pragma unroll
            for (int t = 0; t < 4; t++)
                af[t] = *reinterpret_cast<const bf16x8*>(&qs[kk * 2048 + (t * 16 + l15) * 32 + q * 8]);
#pragma unroll
            for (int u2 = 0; u2 < 2; u2++)
                bf1[u2] = *reinterpret_cast<const bf16x8*>(&W1p[(size_t)(u2 * 16 + l15) * 256 + kk * 32 + q * 8]);
#pragma unroll
            for (int t = 0; t < 4; t++)
#pragma unroll
                for (int u2 = 0; u2 < 2; u2++)
                    acc1[t][u2] = __builtin_amdgcn_mfma_f32_16x16x32_bf16(af[t], bf1[u2], acc1[t][u2], 0, 0, 0);
        }
        __syncthreads();   // prev chunk's GEMM2 Hs reads complete
        // ---- bias + exact GELU -> Hs (swizzled) ----
#pragma unroll
        for (int u2 = 0; u2 < 2; u2++) {
            int col = wn1 + u2 * 16 + l15;
            float bv = b1[j * 128 + col];
#pragma unroll
            for (int t = 0; t < 4; t++)
#pragma unroll
                for (int r = 0; r < 4; r++) {
                    int row = t * 16 + q * 4 + r;
                    float v = acc1[t][u2][r] + bv;
                    v = 0.5f * v * (1.f + erff(v * 0.70710678118f));
                    int bo = (row * 256 + col * 2) ^ ((row & 7) << 4);
                    *(unsigned short*)((char*)Hs + bo) = f2bf(v);
                }
        }
        __syncthreads();   // Hs ready
        // ---- GEMM2: acc2 += Hchunk @ W2chunk (K=128) ----
        const unsigned short* W2p = Wt2 + (size_t)wn2 * 1024 + j * 128;
#pragma unroll
        for (int kk2 = 0; kk2 < 4; kk2++) {
            bf16x8 af2[4], bf2[4];
#pragma unroll
            for (int t = 0; t < 4; t++) {
                int row = t * 16 + l15;
                int bo = (row * 256 + (kk2 * 32 + q * 8) * 2) ^ ((row & 7) << 4);
                af2[t] = *reinterpret_cast<const bf16x8*>((const char*)Hs + bo);
            }
#pragma unroll
            for (int u = 0; u < 4; u++)
                bf2[u] = *reinterpret_cast<const bf16x8*>(&W2p[(size_t)(u * 16 + l15) * 1024 + kk2 * 32 + q * 8]);
#pragma unroll
            for (int t = 0; t < 4; t++)
#pragma unroll
                for (int u = 0; u < 4; u++)
                    acc2[t][u] = __builtin_amdgcn_mfma_f32_16x16x32_bf16(af2[t], bf2[u], acc2[t][u], 0, 0, 0);
        }
    }

    // ---- epilogue: + b2 + residual(q, read from LDS qs) + LN2 -> out f32 ----
    float gg[4], bb[4], bias_v[4];
#pragma unroll
    for (int u = 0; u < 4; u++) {
        int gn = wn2 + u * 16 + l15;
        gg[u] = g[gn]; bb[u] = be[gn]; bias_v[u] = b2[gn];
    }

    float x[4][4][4];     // [t][r][u]
    float ssum[4][4], ssq[4][4];
#pragma unroll
    for (int t = 0; t < 4; t++) {
#pragma unroll
        for (int r = 0; r < 4; r++) {
            int row = t * 16 + q * 4 + r;
            float s = 0.f, sq = 0.f;
#pragma unroll
            for (int u = 0; u < 4; u++) {
                int gn = wn2 + u * 16 + l15;
                float rv = bf2f(qs[(gn >> 5) * 2048 + row * 32 + (gn & 31)]);
                float xx = acc2[t][u][r] + bias_v[u] + rv;
                x[t][r][u] = xx;
                s += xx; sq += xx * xx;
            }
            ssum[t][r] = s; ssq[t][r] = sq;
        }
    }
#pragma unroll
    for (int m = 1; m <= 8; m <<= 1) {
#pragma unroll
        for (int t = 0; t < 4; t++)
#pragma unroll
            for (int r = 0; r < 4; r++) {
                ssum[t][r] += __shfl_xor(ssum[t][r], m);
                ssq[t][r] += __shfl_xor(ssq[t][r], m);
            }
    }
    __syncthreads();   // all qs residual reads + Hs GEMM2 reads done
    float* Ls = (float*)qs;          // [64][4]
    float* Lq = Ls + 256;            // [64][4]
    if (l15 == 0) {
#pragma unroll
        for (int t = 0; t < 4; t++)
#pragma unroll
            for (int r = 0; r < 4; r++) {
                int lr = t * 16 + q * 4 + r;
                Ls[lr * 4 + w] = ssum[t][r];
                Lq[lr * 4 + w] = ssq[t][r];
            }
    }
    __syncthreads();

#pragma unroll
    for (int t = 0; t < 4; t++) {
#pragma unroll
        for (int r = 0; r < 4; r++) {
            int lr = t * 16 + q * 4 + r;
            int gm = m0 + lr;
            float tot = Ls[lr * 4 + 0] + Ls[lr * 4 + 1] + Ls[lr * 4 + 2] + Ls[lr * 4 + 3];
            float totq = Lq[lr * 4 + 0] + Lq[lr * 4 + 1] + Lq[lr * 4 + 2] + Lq[lr * 4 + 3];
            float mean = tot * (1.f / DD);
            float var = totq * (1.f / DD) - mean * mean;
            float rs = rsqrtf(var + EPSLN);
            if (gm < M) {
#pragma unroll
                for (int u = 0; u < 4; u++) {
                    int gn = wn2 + u * 16 + l15;
                    out[(size_t)gm * DD + gn] = (x[t][r][u] - mean) * rs * gg[u] + bb[u];
                }
            }
        }
    }
}

// ---------------------------------------------------------------------------
// Activation casts fused: query -> qbf [52736x256], p3/p4/p5 -> featsb.
// ---------------------------------------------------------------------------
#define QELEMS   13500416   // 52736*256
#define F3ELEMS  10256384   // 40064*256
#define F4ELEMS   2588672   // 10112*256
#define TOTELEMS 27000832

__launch_bounds__(256)
__global__ void cast_acts_k(const float* __restrict__ query, const float* __restrict__ p3,
                            const float* __restrict__ p4, const float* __restrict__ p5,
                            unsigned short* __restrict__ qbf, unsigned short* __restrict__ featsb) {
    int idx4 = (blockIdx.x * 256 + threadIdx.x) * 4;
    if (idx4 >= TOTELEMS) return;
    const float* src; unsigned short* dst; int local, real;
    if (idx4 < QELEMS) {
        src = query; dst = qbf; local = idx4; real = 13440000;
    } else {
        int j = idx4 - QELEMS;
        if (j < F3ELEMS)              { src = p3; dst = featsb;                    local = j;            real = 10240000; }
        else if (j < F3ELEMS + F4ELEMS){ src = p4; dst = featsb + F3ELEMS;         local = j - F3ELEMS;  real = 2560000; }
        else                          { src = p5; dst = featsb + F3ELEMS + F4ELEMS; local = j - F3ELEMS - F4ELEMS; real = 640000; }
    }
    float4 v = make_float4(0.f, 0.f, 0.f, 0.f);
    if (local < real) v = *(const float4*)&src[local];
    ushort4 o;
    o.x = f2bf(v.x); o.y = f2bf(v.y); o.z = f2bf(v.z); o.w = f2bf(v.w);
    *(ushort4*)&dst[local] = o;
}

// ---------------------------------------------------------------------------
// Weight preps: Wtq [384][256] (Woff|Wattn|Wref|0), Wtv, Wto, Wt1, Wt2,
// then biasq[384] f32 (boff|battn|bref|0).
// ---------------------------------------------------------------------------
#define WTQ_E   98304
#define WTV_E   (WTQ_E + 65536)     // 163840
#define WTO_E   (WTV_E + 65536)     // 229376
#define WT1_E   (WTO_E + 262144)    // 491520
#define WT2_E   (WT1_E + 262144)    // 753664
#define PREP_TOT (WT2_E + 384)

__launch_bounds__(256)
__global__ void prep_w_k(const float* __restrict__ Woff, const float* __restrict__ Wattn,
                         const float* __restrict__ Wref, const float* __restrict__ Wv,
                         const float* __restrict__ Wo, const float* __restrict__ W1,
                         const float* __restrict__ W2, const float* __restrict__ boff,
                         const float* __restrict__ battn, const float* __restrict__ bref,
                         unsigned short* __restrict__ warena, float* __restrict__ biasq) {
    int i = blockIdx.x * 256 + threadIdx.x;
    if (i >= PREP_TOT) return;
    if (i >= WT2_E) {
        int t = i - WT2_E;
        biasq[t] = (t < 192) ? boff[t] : (t < 288 ? battn[t - 192] : (t < 290 ? bref[t - 288] : 0.f));
        return;
    }
    float v;
    if (i < WTQ_E) {
        int n = i >> 8, k = i & 255;
        v = (n < 192) ? Woff[k * 192 + n]
          : (n < 288) ? Wattn[k * 96 + (n - 192)]
          : (n < 290) ? Wref[k * 2 + (n - 288)] : 0.f;
    } else if (i < WTV_E) {
        int j = i - WTQ_E; int n = j >> 8, k = j & 255;
        v = Wv[k * 256 + n];
    } else if (i < WTO_E) {
        int j = i - WTV_E; int n = j >> 8, k = j & 255;
        v = Wo[k * 256 + n];
    } else if (i < WT1_E) {
        int j = i - WTO_E; int n = j >> 8, k = j & 255;
        v = W1[k * 1024 + n];
    } else {
        int j = i - WT1_E; int n = j >> 10, k = j & 1023;
        v = W2[k * 256 + n];
    }
    warena[i] = f2bf(v);
}

// ---------------------------------------------------------------------------
// softmax over groups of 12 from projb (ldc 320, offset 192) -> bf16 aw.
// ---------------------------------------------------------------------------
__launch_bounds__(256)
__global__ void softmax12_k(const float* __restrict__ projb, unsigned short* __restrict__ aw) {
    int rh = blockIdx.x * 256 + threadIdx.x;
    if (rh >= MROWS * NHH) return;
    int bn = rh >> 3, h = rh & 7;
    const float* p = projb + (size_t)bn * 320 + 192 + h * 12;
    float v[12], mx = -1e30f;
#pragma unroll
    for (int i = 0; i < 12; i++) { v[i] = p[i]; mx = fmaxf(mx, v[i]); }
    float s = 0.f;
#pragma unroll
    for (int i = 0; i < 12; i++) { v[i] = expf(v[i] - mx); s += v[i]; }
    float inv = 1.f / s;
    unsigned short* o = aw + (size_t)rh * 12;
#pragma unroll
    for (int i = 0; i < 12; i++) o[i] = f2bf(v[i] * inv);
}

// ---------------------------------------------------------------------------
// Deformable sampling v4: 128 threads = 2 waves, one (b,n) per wave.
// Ref logits read from projb cols 288/289 (sigmoid here). Packed LDS
// {weight, byte-offset} pairs -> one ds_read_b64 per corner.
// ---------------------------------------------------------------------------
__launch_bounds__(128)
__global__ void sample_k(const unsigned short* __restrict__ val, const float* __restrict__ projb,
                         const unsigned short* __restrict__ aw,
                         unsigned short* __restrict__ out) {
    const int wv = threadIdx.x >> 6;
    const int lane = threadIdx.x & 63;
    const int bn = blockIdx.x * 2 + wv;
    const int b = bn / NTOT;
    __shared__ uint2 sc[2][96][4];

    const float* prow = projb + (size_t)bn * 320;
    float rx = 1.f / (1.f + expf(-prow[288]));
    float ry = 1.f / (1.f + expf(-prow[289]));
    for (int s0 = lane; s0 < 96; s0 += 64) {
        const int lp = s0 % 12;
        const int l = lp >> 2;
        int Hl, Wl, loff;
        if (l == 0)      { Hl = 100; Wl = 100; loff = 0; }
        else if (l == 1) { Hl = 50;  Wl = 50;  loff = 10000; }
        else             { Hl = 25;  Wl = 25;  loff = 12500; }
        float ox = prow[s0 * 2 + 0];
        float oy = prow[s0 * 2 + 1];
        float a  = bf2f(aw[(size_t)bn * 96 + s0]);
        float x = rx * (float)Wl + ox - 0.5f;
        float y = ry * (float)Hl + oy - 0.5f;
        x = fminf(fmaxf(x, -1e4f), 1e4f);
        y = fminf(fmaxf(y, -1e4f), 1e4f);
        float x0f = floorf(x), y0f = floorf(y);
        float lx = x - x0f, ly = y - y0f;
        int x0 = (int)x0f, y0 = (int)y0f;
#pragma unroll
        for (int c = 0; c < 4; c++) {
            int xi = x0 + (c & 1);
            int yi = y0 + (c >> 1);
            bool ok = (xi >= 0) && (xi < Wl) && (yi >= 0) && (yi < Hl);
            int xc = min(max(xi, 0), Wl - 1);
            int yc = min(max(yi, 0), Hl - 1);
            int idx = b * NTOT + loff + yc * Wl + xc;
            float wgt = ((c & 1) ? lx : 1.f - lx) * ((c >> 1) ? ly : 1.f - ly);
            sc[wv][s0][c] = make_uint2(__float_as_uint(ok ? a * wgt : 0.f), (unsigned)(idx * 512));
        }
    }
    __syncthreads();

    const int h = lane >> 3;
    const int dq = (lane & 7) * 4;
    const char* vb = (const char*)val + h * 64 + dq * 2;
    float a0 = 0.f, a1 = 0.f, a2 = 0.f, a3 = 0.f;
#pragma unroll
    for (int lp = 0; lp < 12; lp++) {
        int s = h * 12 + lp;
#pragma unroll
        for (int c = 0; c < 4; c++) {
            uint2 p = sc[wv][s][c];
            float wgt = __uint_as_float(p.x);
            uint2 u = *(const uint2*)(vb + p.y);
            a0 += wgt * __uint_as_float(u.x << 16);
            a1 += wgt * __uint_as_float(u.x & 0xFFFF0000u);
            a2 += wgt * __uint_as_float(u.y << 16);
            a3 += wgt * __uint_as_float(u.y & 0xFFFF0000u);
        }
    }
    uint2 ov;
    ov.x = (unsigned)f2bf(a0) | ((unsigned)f2bf(a1) << 16);
    ov.y = (unsigned)f2bf(a2) | ((unsigned)f2bf(a3) << 16);
    *(uint2*)(out + (size_t)bn * DD + h * 32 + dq) = ov;
}

// ---------------------------------------------------------------------------
extern "C" void kernel_launch(void* const* d_in, const int* in_sizes, int n_in,
                              void* d_out, int out_size, void* d_ws, size_t ws_size,
                              hipStream_t stream) {
    const float* query = (const float*)d_in[0];
    const float* p3    = (const float*)d_in[1];
    const float* p4    = (const float*)d_in[2];
    const float* p5    = (const float*)d_in[3];
    const float* Wv    = (const float*)d_in[4];
    const float* bv    = (const float*)d_in[5];
    const float* Woff  = (const float*)d_in[6];
    const float* boff  = (const float*)d_in[7];
    const float* Wattn = (const float*)d_in[8];
    const float* battn = (const float*)d_in[9];
    const float* Wref  = (const float*)d_in[10];
    const float* bref  = (const float*)d_in[11];
    const float* Wo    = (const float*)d_in[12];
    const float* bo    = (const float*)d_in[13];
    const float* W1    = (const float*)d_in[14];
    const float* b1    = (const float*)d_in[15];
    const float* W2    = (const float*)d_in[16];
    const float* b2    = (const float*)d_in[17];
    const float* g1    = (const float*)d_in[18];
    const float* be1   = (const float*)d_in[19];
    const float* g2    = (const float*)d_in[20];
    const float* be2   = (const float*)d_in[21];
    float* outp = (float*)d_out;

    // ---- workspace layout (bytes), total ~186.9 MB ----
    char* wsb = (char*)d_ws;
    unsigned short* qbf    = (unsigned short*)(wsb + 0);           // 52736x256 bf16  [0, 27000832)
    float*          projb  = (float*)(wsb + 27000832);             // 52736x320 f32   [.., 94502912)
    unsigned short* awb    = (unsigned short*)(wsb + 94502912);    // 52500x96 bf16   [.., 104582912)
    unsigned short* featsb = (unsigned short*)(wsb + 104582912);   // 52736x256 bf16  [.., 131583744)
    unsigned short* valb   = (unsigned short*)(wsb + 131583744);   // 52500x256 bf16  [.., 158463744)
    unsigned short* sampb  = (unsigned short*)(wsb + 158463744);   // 52608x256 bf16  [.., 185399296)
    unsigned short* warena = (unsigned short*)(wsb + 185399296);   // 753664 bf16     [.., 186906624)
    float*          biasq  = (float*)(wsb + 186906624);            // 384 f32
    // NOTE: hid intermediate eliminated — FFN is fused (ffn_k), no 108 MB round-trip.

    unsigned short* Wtq = warena;                 // [384][256]
    unsigned short* Wtv = warena + WTQ_E;
    unsigned short* Wto = warena + WTV_E;
    unsigned short* Wt1 = warena + WTO_E;         // [1024][256]
    unsigned short* Wt2 = warena + WT1_E;         // [256][1024]

    // 1) activation casts
    cast_acts_k<<<dim3(TOTELEMS / 4 / 256), 256, 0, stream>>>(query, p3, p4, p5, qbf, featsb);
    // 2) weight preps (incl. Wref/bref folded into q-proj weight)
    prep_w_k<<<dim3((PREP_TOT + 255) / 256), 256, 0, stream>>>(
        Woff, Wattn, Wref, Wv, Wo, W1, W2, boff, battn, bref, warena, biasq);
    // 3) combined q projection: [off | attn logits | ref logits] -> projb [.,320]
    mm_k<EPI_F32, float><<<dim3(MPAD / 128, 3), 256, 0, stream>>>(
        qbf, Wtq, biasq, projb, MROWS, 256, 290, 320, 0);
    // 4) softmax -> aw bf16
    softmax12_k<<<dim3((MROWS * NHH + 255) / 256), 256, 0, stream>>>(projb, awb);
    // 5) value projection (single dispatch, per-row segment remap)
    mm_k<EPI_VALSEG, unsigned short><<<dim3(MPAD / 128, 2), 256, 0, stream>>>(
        featsb, Wtv, bv, valb, 0, 256, 256, 256, 0);
    // 6) deformable sampling (2 query points per block)
    sample_k<<<dim3(MROWS / 2), 128, 0, stream>>>(valb, projb, awb, sampb);
    // 7) Wo + residual(query f32) + LN1 -> qbf
    gemmln_k<float, unsigned short><<<dim3((MROWS + 63) / 64), 256, 0, stream>>>(
        sampb, Wto, bo, query, g1, be1, qbf, MROWS, 256);
    // 8) fused FFN: W1 + GELU + W2 + residual(qbf) + LN2 -> out f32
    ffn_k<<<dim3((MROWS + 63) / 64), 256, 0, stream>>>(
        qbf, Wt1, b1, Wt2, b2, g2, be2, outp, MROWS);
}

// Round 5
// 551.649 us; speedup vs baseline: 1.0851x; 1.0244x over previous
//
#include <hip/hip_runtime.h>
#include <math.h>

// Problem constants
#define BQ    4
#define NTOT  13125
#define DD    256
#define NHH   8
#define FFD   1024
#define EPSLN 1e-5f
#define MROWS (BQ * NTOT)        // 52500
#define MPAD  52736              // 412*128

typedef __bf16 bf16_t;
typedef bf16_t bf16x8 __attribute__((ext_vector_type(8)));
typedef float floatx4 __attribute__((ext_vector_type(4)));

__device__ __forceinline__ unsigned short f2bf(float f) {
    unsigned u = __float_as_uint(f);
    return (unsigned short)((u + 0x7FFFu + ((u >> 16) & 1u)) >> 16);
}
__device__ __forceinline__ float bf2f(unsigned short h) {
    return __uint_as_float(((unsigned)h) << 16);
}

typedef const __attribute__((address_space(1))) unsigned int* gptr_t;
typedef __attribute__((address_space(3))) unsigned int* lptr_t;
__device__ __forceinline__ void gld16(const void* g, void* l) {
    __builtin_amdgcn_global_load_lds((gptr_t)g, (lptr_t)l, 16, 0, 0);
}

enum { EPI_F32 = 0, EPI_GELU = 2, EPI_VALSEG = 3 };

// Map padded concatenated feature row -> value-buffer row (b*NTOT + loff + nl)
__device__ __forceinline__ int val_row(int gm) {
    if (gm < 40064) {
        if (gm >= 40000) return -1;
        int b = gm / 10000; int nl = gm - b * 10000;
        return b * NTOT + nl;
    } else if (gm < 50176) {
        int r = gm - 40064;
        if (r >= 10000) return -1;
        int b = r / 2500; int nl = r - b * 2500;
        return b * NTOT + 10000 + nl;
    } else {
        int r = gm - 50176;
        if (r >= 2500) return -1;
        int b = r / 625; int nl = r - b * 625;
        return b * NTOT + 12500 + nl;
    }
}

// ---------------------------------------------------------------------------
// bf16 MFMA GEMM (m97 structure): A [Mpad,K] bf16, Bt [Npad,K] bf16.
// 128x128 tile, BK=32, 4 waves, 4x4 grid of 16x16x32 mfma.
// ---------------------------------------------------------------------------
template <int EPI, typename OutT>
__launch_bounds__(256)
__global__ void mm_k(const unsigned short* __restrict__ A,
                     const unsigned short* __restrict__ Bt,
                     const float* __restrict__ bias, OutT* __restrict__ C,
                     int M, int K, int Nout, int ldc, int Mstore) {
    __shared__ __align__(16) unsigned short As[128 * 32];
    __shared__ __align__(16) unsigned short Bs[128 * 32];

    const int tid = threadIdx.x;
    const int m0 = blockIdx.x * 128;
    const int n0 = blockIdx.y * 128;
    const int w = tid >> 6, lane = tid & 63;
    const int q = lane >> 4, l15 = lane & 15;
    const int wm = (w & 1) * 64, wn = (w >> 1) * 64;

    const int sr = tid >> 2;
    const int sk = (tid & 3) * 8;

    const unsigned short* Ag = A + (size_t)(m0 + sr) * K + sk;
    const unsigned short* Bg = Bt + (size_t)(n0 + sr) * K + sk;
    char* AsB = (char*)As;
    char* BsB = (char*)Bs;

    floatx4 acc[4][4];
#pragma unroll
    for (int t = 0; t < 4; t++)
#pragma unroll
        for (int u = 0; u < 4; u++) {
            floatx4 z = {0.f, 0.f, 0.f, 0.f};
            acc[t][u] = z;
        }

    for (int k0 = 0; k0 < K; k0 += 32) {
        gld16(Ag + k0, AsB + tid * 16);
        gld16(Ag + (size_t)64 * K + k0, AsB + 4096 + tid * 16);
        gld16(Bg + k0, BsB + tid * 16);
        gld16(Bg + (size_t)64 * K + k0, BsB + 4096 + tid * 16);
        __syncthreads();

        bf16x8 af[4], bfr[4];
#pragma unroll
        for (int t = 0; t < 4; t++)
            af[t] = *reinterpret_cast<const bf16x8*>(&As[(wm + t * 16 + l15) * 32 + q * 8]);
#pragma unroll
        for (int u = 0; u < 4; u++)
            bfr[u] = *reinterpret_cast<const bf16x8*>(&Bs[(wn + u * 16 + l15) * 32 + q * 8]);
#pragma unroll
        for (int t = 0; t < 4; t++)
#pragma unroll
            for (int u = 0; u < 4; u++)
                acc[t][u] = __builtin_amdgcn_mfma_f32_16x16x32_bf16(af[t], bfr[u], acc[t][u], 0, 0, 0);
        __syncthreads();
    }

    float bias_v[4];
#pragma unroll
    for (int u = 0; u < 4; u++) {
        int gn = n0 + wn + u * 16 + l15;
        bias_v[u] = (gn < Nout) ? bias[gn] : 0.f;
    }

#pragma unroll
    for (int t = 0; t < 4; t++) {
#pragma unroll
        for (int r = 0; r < 4; r++) {
            int gm = m0 + wm + t * 16 + q * 4 + r;
            int orow = gm;
            if (EPI == EPI_VALSEG) orow = val_row(gm);
#pragma unroll
            for (int u = 0; u < 4; u++) {
                int gn = n0 + wn + u * 16 + l15;
                if (gn >= Nout) continue;
                float v = acc[t][u][r] + bias_v[u];
                if (EPI == EPI_GELU) {
                    v = 0.5f * v * (1.f + erff(v * 0.70710678118f));
                    if (gm < Mstore) {
                        float ov = (gm < M) ? v : 0.f;
                        ((unsigned short*)C)[(size_t)gm * ldc + gn] = f2bf(ov);
                    }
                } else if (EPI == EPI_VALSEG) {
                    if (orow >= 0)
                        ((unsigned short*)C)[(size_t)orow * ldc + gn] = f2bf(v);
                } else {
                    if (gm < M) ((float*)C)[(size_t)gm * ldc + gn] = v;
                }
            }
        }
    }
}

// ---------------------------------------------------------------------------
// Fused GEMM (N=256) + bias + residual + LayerNorm.
// Tile 64 rows x 256 cols (full row), 4 waves col-split 64 each.
// RT: residual dtype (float or ushort/bf16); OT: output (ushort/bf16 or float).
// ---------------------------------------------------------------------------
template <typename RT, typename OT>
__launch_bounds__(256)
__global__ void gemmln_k(const unsigned short* __restrict__ A,
                         const unsigned short* __restrict__ Bt,
                         const float* __restrict__ bias, const RT* __restrict__ res,
                         const float* __restrict__ g, const float* __restrict__ be,
                         OT* __restrict__ out, int M, int K) {
    __shared__ __align__(16) unsigned short As[64 * 32];    // 4 KB
    __shared__ __align__(16) unsigned short Bs[256 * 32];   // 16 KB

    const int tid = threadIdx.x;
    const int m0 = blockIdx.x * 64;
    const int w = tid >> 6, lane = tid & 63;
    const int q = lane >> 4, l15 = lane & 15;
    const int wn = w * 64;

    const int sr = tid >> 2;
    const int sk = (tid & 3) * 8;
    const unsigned short* Ag = A + (size_t)(m0 + sr) * K + sk;
    const unsigned short* Bg = Bt + (size_t)sr * K + sk;
    char* AsB = (char*)As;
    char* BsB = (char*)Bs;

    floatx4 acc[4][4];
#pragma unroll
    for (int t = 0; t < 4; t++)
#pragma unroll
        for (int u = 0; u < 4; u++) {
            floatx4 z = {0.f, 0.f, 0.f, 0.f};
            acc[t][u] = z;
        }

    for (int k0 = 0; k0 < K; k0 += 32) {
        gld16(Ag + k0, AsB + tid * 16);
#pragma unroll
        for (int j = 0; j < 4; j++)
            gld16(Bg + (size_t)j * 64 * K + k0, BsB + j * 4096 + tid * 16);
        __syncthreads();

        bf16x8 af[4], bfr[4];
#pragma unroll
        for (int t = 0; t < 4; t++)
            af[t] = *reinterpret_cast<const bf16x8*>(&As[(t * 16 + l15) * 32 + q * 8]);
#pragma unroll
        for (int u = 0; u < 4; u++)
            bfr[u] = *reinterpret_cast<const bf16x8*>(&Bs[(wn + u * 16 + l15) * 32 + q * 8]);
#pragma unroll
        for (int t = 0; t < 4; t++)
#pragma unroll
            for (int u = 0; u < 4; u++)
                acc[t][u] = __builtin_amdgcn_mfma_f32_16x16x32_bf16(af[t], bfr[u], acc[t][u], 0, 0, 0);
        __syncthreads();
    }
    // after final sync: all LDS frag reads done; reuse As for row stats.

    float gg[4], bb[4], bias_v[4];
#pragma unroll
    for (int u = 0; u < 4; u++) {
        int gn = wn + u * 16 + l15;
        gg[u] = g[gn]; bb[u] = be[gn]; bias_v[u] = bias[gn];
    }

    float x[4][4][4];     // [t][r][u]
    float ssum[4][4], ssq[4][4];
#pragma unroll
    for (int t = 0; t < 4; t++) {
#pragma unroll
        for (int r = 0; r < 4; r++) {
            int gm = m0 + t * 16 + q * 4 + r;
            bool valid = gm < M;
            float s = 0.f, sq = 0.f;
#pragma unroll
            for (int u = 0; u < 4; u++) {
                int gn = wn + u * 16 + l15;
                float rv = 0.f;
                if (valid) {
                    if (sizeof(RT) == 2)
                        rv = bf2f(((const unsigned short*)res)[(size_t)gm * DD + gn]);
                    else
                        rv = ((const float*)res)[(size_t)gm * DD + gn];
                }
                float xx = acc[t][u][r] + bias_v[u] + rv;
                x[t][r][u] = xx;
                s += xx; sq += xx * xx;
            }
            ssum[t][r] = s; ssq[t][r] = sq;
        }
    }
    // reduce over the 16 lanes of each quad (cols within this wave)
#pragma unroll
    for (int m = 1; m <= 8; m <<= 1) {
#pragma unroll
        for (int t = 0; t < 4; t++)
#pragma unroll
            for (int r = 0; r < 4; r++) {
                ssum[t][r] += __shfl_xor(ssum[t][r], m);
                ssq[t][r] += __shfl_xor(ssq[t][r], m);
            }
    }
    // cross-wave reduction via LDS (reuse As region)
    float* Ls = (float*)As;          // [64][4]
    float* Lq = Ls + 256;            // [64][4]
    if (l15 == 0) {
#pragma unroll
        for (int t = 0; t < 4; t++)
#pragma unroll
            for (int r = 0; r < 4; r++) {
                int lr = t * 16 + q * 4 + r;
                Ls[lr * 4 + w] = ssum[t][r];
                Lq[lr * 4 + w] = ssq[t][r];
            }
    }
    __syncthreads();

#pragma unroll
    for (int t = 0; t < 4; t++) {
#pragma unroll
        for (int r = 0; r < 4; r++) {
            int lr = t * 16 + q * 4 + r;
            int gm = m0 + lr;
            float tot = Ls[lr * 4 + 0] + Ls[lr * 4 + 1] + Ls[lr * 4 + 2] + Ls[lr * 4 + 3];
            float totq = Lq[lr * 4 + 0] + Lq[lr * 4 + 1] + Lq[lr * 4 + 2] + Lq[lr * 4 + 3];
            float mean = tot * (1.f / DD);
            float var = totq * (1.f / DD) - mean * mean;
            float rs = rsqrtf(var + EPSLN);
            if (gm < M) {
#pragma unroll
                for (int u = 0; u < 4; u++) {
                    int gn = wn + u * 16 + l15;
                    float o = (x[t][r][u] - mean) * rs * gg[u] + bb[u];
                    if (sizeof(OT) == 2)
                        ((unsigned short*)out)[(size_t)gm * DD + gn] = f2bf(o);
                    else
                        ((float*)out)[(size_t)gm * DD + gn] = o;
                }
            }
        }
    }
}

// ---------------------------------------------------------------------------
// Fused FFN v2: 8 waves / 512 threads per 64-row block (was 4 waves).
// Counters (r4): 182us, MfmaUtil 12%, VALU 22%, Occ 18% -> latency-bound.
// 8-wave halves per-wave N-slice (GEMM1: 16 hid cols, GEMM2: 32 out cols),
// halving per-wave regs -> 2 blocks/CU x 8 waves = 16 waves/CU (was 12) and
// halves per-wave in-loop weight-load count. Same LDS (48KB), same erff.
// __launch_bounds__(512,4) pins VGPR<=128 so occupancy target holds.
// ---------------------------------------------------------------------------
__launch_bounds__(512, 4)
__global__ void ffn_k(const unsigned short* __restrict__ A,     // qbf [MPAD][256], rows>=M are zero
                      const unsigned short* __restrict__ Wt1,   // [1024][256]
                      const float* __restrict__ b1,
                      const unsigned short* __restrict__ Wt2,   // [256][1024]
                      const float* __restrict__ b2,
                      const float* __restrict__ g, const float* __restrict__ be,
                      float* __restrict__ out, int M) {
    __shared__ __align__(16) unsigned short qs[8 * 64 * 32];   // 32 KB: [kk][row][k8]
    __shared__ __align__(16) unsigned short Hs[64 * 128];      // 16 KB, swizzled

    const int tid = threadIdx.x;
    const int m0 = blockIdx.x * 64;
    const int w = tid >> 6, lane = tid & 63;
    const int q = lane >> 4, l15 = lane & 15;

    // stage q tile: 4 passes; each wave-issue fills a contiguous 1KB LDS run
    // (gld16 dest MUST be wave-uniform base + lane*16).
    {
        char* qsB = (char*)qs;
#pragma unroll
        for (int p = 0; p < 4; p++) {
            int idx = p * 8 + w;                 // 1KB unit, 0..31 (wave-uniform)
            int kkb = idx >> 2;                  // k-block 0..7
            int row = (idx & 3) * 16 + (lane >> 2);
            int c = lane & 3;                    // 16B chunk within row
            gld16(A + (size_t)(m0 + row) * 256 + kkb * 32 + c * 8,
                  qsB + idx * 1024 + lane * 16);
        }
    }

    floatx4 acc2[4][2];
#pragma unroll
    for (int t = 0; t < 4; t++)
#pragma unroll
        for (int u = 0; u < 2; u++) {
            floatx4 z = {0.f, 0.f, 0.f, 0.f};
            acc2[t][u] = z;
        }

    __syncthreads();   // qs ready

#pragma unroll 1
    for (int j = 0; j < 8; j++) {
        // ---- GEMM1: H[64][16 cols (w)] of chunk j = q @ W1 (K=256) ----
        floatx4 acc1[4];
#pragma unroll
        for (int t = 0; t < 4; t++) {
            floatx4 z = {0.f, 0.f, 0.f, 0.f};
            acc1[t] = z;
        }
        const unsigned short* W1p = Wt1 + (size_t)(j * 128 + w * 16 + l15) * 256;
#pragma unroll
        for (int kk = 0; kk < 8; kk++) {
            bf16x8 af[4], bf1;
#pragma unroll
            for (int t = 0; t < 4; t++)
                af[t] = *reinterpret_cast<const bf16x8*>(&qs[kk * 2048 + (t * 16 + l15) * 32 + q * 8]);
            bf1 = *reinterpret_cast<const bf16x8*>(&W1p[kk * 32 + q * 8]);
#pragma unroll
            for (int t = 0; t < 4; t++)
                acc1[t] = __builtin_amdgcn_mfma_f32_16x16x32_bf16(af[t], bf1, acc1[t], 0, 0, 0);
        }
        __syncthreads();   // prev chunk's GEMM2 Hs reads complete
        // ---- bias + exact GELU -> Hs (swizzled); each lane owns one col ----
        {
            int col = w * 16 + l15;
            float bv = b1[j * 128 + col];
#pragma unroll
            for (int t = 0; t < 4; t++)
#pragma unroll
                for (int r = 0; r < 4; r++) {
                    int row = t * 16 + q * 4 + r;
                    float v = acc1[t][r] + bv;
                    v = 0.5f * v * (1.f + erff(v * 0.70710678118f));
                    int bo = (row * 256 + col * 2) ^ ((row & 7) << 4);
                    *(unsigned short*)((char*)Hs + bo) = f2bf(v);
                }
        }
        __syncthreads();   // Hs ready
        // ---- GEMM2: acc2 += Hchunk @ W2chunk (K=128), wave cols w*32 ----
        const unsigned short* W2p = Wt2 + (size_t)(w * 32) * 1024 + j * 128;
#pragma unroll
        for (int kk2 = 0; kk2 < 4; kk2++) {
            bf16x8 af2[4], bf2[2];
#pragma unroll
            for (int t = 0; t < 4; t++) {
                int row = t * 16 + l15;
                int bo = (row * 256 + (kk2 * 32 + q * 8) * 2) ^ ((row & 7) << 4);
                af2[t] = *reinterpret_cast<const bf16x8*>((const char*)Hs + bo);
            }
#pragma unroll
            for (int u = 0; u < 2; u++)
                bf2[u] = *reinterpret_cast<const bf16x8*>(&W2p[(size_t)(u * 16 + l15) * 1024 + kk2 * 32 + q * 8]);
#pragma unroll
            for (int t = 0; t < 4; t++)
#pragma unroll
                for (int u = 0; u < 2; u++)
                    acc2[t][u] = __builtin_amdgcn_mfma_f32_16x16x32_bf16(af2[t], bf2[u], acc2[t][u], 0, 0, 0);
        }
    }

    // ---- epilogue: + b2 + residual(q from LDS qs) + LN2 -> out f32 ----
    const int wn2 = w * 32;
    float gg[2], bb[2], bias_v[2];
#pragma unroll
    for (int u = 0; u < 2; u++) {
        int gn = wn2 + u * 16 + l15;
        gg[u] = g[gn]; bb[u] = be[gn]; bias_v[u] = b2[gn];
    }

    float x[4][4][2];     // [t][r][u]
    float ssum[4][4], ssq[4][4];
#pragma unroll
    for (int t = 0; t < 4; t++) {
#pragma unroll
        for (int r = 0; r < 4; r++) {
            int row = t * 16 + q * 4 + r;
            float s = 0.f, sq = 0.f;
#pragma unroll
            for (int u = 0; u < 2; u++) {
                int gn = wn2 + u * 16 + l15;
                float rv = bf2f(qs[(gn >> 5) * 2048 + row * 32 + (gn & 31)]);
                float xx = acc2[t][u][r] + bias_v[u] + rv;
                x[t][r][u] = xx;
                s += xx; sq += xx * xx;
            }
            ssum[t][r] = s; ssq[t][r] = sq;
        }
    }
#pragma unroll
    for (int m = 1; m <= 8; m <<= 1) {
#pragma unroll
        for (int t = 0; t < 4; t++)
#pragma unroll
            for (int r = 0; r < 4; r++) {
                ssum[t][r] += __shfl_xor(ssum[t][r], m);
                ssq[t][r] += __shfl_xor(ssq[t][r], m);
            }
    }
    __syncthreads();   // all qs residual reads + Hs GEMM2 reads done
    float* Ls = (float*)qs;          // [64][8]
    float* Lq = Ls + 512;            // [64][8]
    if (l15 == 0) {
#pragma unroll
        for (int t = 0; t < 4; t++)
#pragma unroll
            for (int r = 0; r < 4; r++) {
                int lr = t * 16 + q * 4 + r;
                Ls[lr * 8 + w] = ssum[t][r];
                Lq[lr * 8 + w] = ssq[t][r];
            }
    }
    __syncthreads();

#pragma unroll
    for (int t = 0; t < 4; t++) {
#pragma unroll
        for (int r = 0; r < 4; r++) {
            int lr = t * 16 + q * 4 + r;
            int gm = m0 + lr;
            float tot = 0.f, totq = 0.f;
#pragma unroll
            for (int ww = 0; ww < 8; ww++) {
                tot += Ls[lr * 8 + ww];
                totq += Lq[lr * 8 + ww];
            }
            float mean = tot * (1.f / DD);
            float var = totq * (1.f / DD) - mean * mean;
            float rs = rsqrtf(var + EPSLN);
            if (gm < M) {
#pragma unroll
                for (int u = 0; u < 2; u++) {
                    int gn = wn2 + u * 16 + l15;
                    out[(size_t)gm * DD + gn] = (x[t][r][u] - mean) * rs * gg[u] + bb[u];
                }
            }
        }
    }
}

// ---------------------------------------------------------------------------
// Activation casts fused: query -> qbf [52736x256], p3/p4/p5 -> featsb.
// ---------------------------------------------------------------------------
#define QELEMS   13500416   // 52736*256
#define F3ELEMS  10256384   // 40064*256
#define F4ELEMS   2588672   // 10112*256
#define TOTELEMS 27000832

__launch_bounds__(256)
__global__ void cast_acts_k(const float* __restrict__ query, const float* __restrict__ p3,
                            const float* __restrict__ p4, const float* __restrict__ p5,
                            unsigned short* __restrict__ qbf, unsigned short* __restrict__ featsb) {
    int idx4 = (blockIdx.x * 256 + threadIdx.x) * 4;
    if (idx4 >= TOTELEMS) return;
    const float* src; unsigned short* dst; int local, real;
    if (idx4 < QELEMS) {
        src = query; dst = qbf; local = idx4; real = 13440000;
    } else {
        int j = idx4 - QELEMS;
        if (j < F3ELEMS)              { src = p3; dst = featsb;                    local = j;            real = 10240000; }
        else if (j < F3ELEMS + F4ELEMS){ src = p4; dst = featsb + F3ELEMS;         local = j - F3ELEMS;  real = 2560000; }
        else                          { src = p5; dst = featsb + F3ELEMS + F4ELEMS; local = j - F3ELEMS - F4ELEMS; real = 640000; }
    }
    float4 v = make_float4(0.f, 0.f, 0.f, 0.f);
    if (local < real) v = *(const float4*)&src[local];
    ushort4 o;
    o.x = f2bf(v.x); o.y = f2bf(v.y); o.z = f2bf(v.z); o.w = f2bf(v.w);
    *(ushort4*)&dst[local] = o;
}

// ---------------------------------------------------------------------------
// Weight preps: Wtq [384][256] (Woff|Wattn|Wref|0), Wtv, Wto, Wt1, Wt2,
// then biasq[384] f32 (boff|battn|bref|0).
// ---------------------------------------------------------------------------
#define WTQ_E   98304
#define WTV_E   (WTQ_E + 65536)     // 163840
#define WTO_E   (WTV_E + 65536)     // 229376
#define WT1_E   (WTO_E + 262144)    // 491520
#define WT2_E   (WT1_E + 262144)    // 753664
#define PREP_TOT (WT2_E + 384)

__launch_bounds__(256)
__global__ void prep_w_k(const float* __restrict__ Woff, const float* __restrict__ Wattn,
                         const float* __restrict__ Wref, const float* __restrict__ Wv,
                         const float* __restrict__ Wo, const float* __restrict__ W1,
                         const float* __restrict__ W2, const float* __restrict__ boff,
                         const float* __restrict__ battn, const float* __restrict__ bref,
                         unsigned short* __restrict__ warena, float* __restrict__ biasq) {
    int i = blockIdx.x * 256 + threadIdx.x;
    if (i >= PREP_TOT) return;
    if (i >= WT2_E) {
        int t = i - WT2_E;
        biasq[t] = (t < 192) ? boff[t] : (t < 288 ? battn[t - 192] : (t < 290 ? bref[t - 288] : 0.f));
        return;
    }
    float v;
    if (i < WTQ_E) {
        int n = i >> 8, k = i & 255;
        v = (n < 192) ? Woff[k * 192 + n]
          : (n < 288) ? Wattn[k * 96 + (n - 192)]
          : (n < 290) ? Wref[k * 2 + (n - 288)] : 0.f;
    } else if (i < WTV_E) {
        int j = i - WTQ_E; int n = j >> 8, k = j & 255;
        v = Wv[k * 256 + n];
    } else if (i < WTO_E) {
        int j = i - WTV_E; int n = j >> 8, k = j & 255;
        v = Wo[k * 256 + n];
    } else if (i < WT1_E) {
        int j = i - WTO_E; int n = j >> 8, k = j & 255;
        v = W1[k * 1024 + n];
    } else {
        int j = i - WT1_E; int n = j >> 10, k = j & 1023;
        v = W2[k * 256 + n];
    }
    warena[i] = f2bf(v);
}

// ---------------------------------------------------------------------------
// softmax over groups of 12 from projb (ldc 320, offset 192) -> bf16 aw.
// ---------------------------------------------------------------------------
__launch_bounds__(256)
__global__ void softmax12_k(const float* __restrict__ projb, unsigned short* __restrict__ aw) {
    int rh = blockIdx.x * 256 + threadIdx.x;
    if (rh >= MROWS * NHH) return;
    int bn = rh >> 3, h = rh & 7;
    const float* p = projb + (size_t)bn * 320 + 192 + h * 12;
    float v[12], mx = -1e30f;
#pragma unroll
    for (int i = 0; i < 12; i++) { v[i] = p[i]; mx = fmaxf(mx, v[i]); }
    float s = 0.f;
#pragma unroll
    for (int i = 0; i < 12; i++) { v[i] = expf(v[i] - mx); s += v[i]; }
    float inv = 1.f / s;
    unsigned short* o = aw + (size_t)rh * 12;
#pragma unroll
    for (int i = 0; i < 12; i++) o[i] = f2bf(v[i] * inv);
}

// ---------------------------------------------------------------------------
// Deformable sampling v4: 128 threads = 2 waves, one (b,n) per wave.
// Ref logits read from projb cols 288/289 (sigmoid here). Packed LDS
// {weight, byte-offset} pairs -> one ds_read_b64 per corner.
// ---------------------------------------------------------------------------
__launch_bounds__(128)
__global__ void sample_k(const unsigned short* __restrict__ val, const float* __restrict__ projb,
                         const unsigned short* __restrict__ aw,
                         unsigned short* __restrict__ out) {
    const int wv = threadIdx.x >> 6;
    const int lane = threadIdx.x & 63;
    const int bn = blockIdx.x * 2 + wv;
    const int b = bn / NTOT;
    __shared__ uint2 sc[2][96][4];

    const float* prow = projb + (size_t)bn * 320;
    float rx = 1.f / (1.f + expf(-prow[288]));
    float ry = 1.f / (1.f + expf(-prow[289]));
    for (int s0 = lane; s0 < 96; s0 += 64) {
        const int lp = s0 % 12;
        const int l = lp >> 2;
        int Hl, Wl, loff;
        if (l == 0)      { Hl = 100; Wl = 100; loff = 0; }
        else if (l == 1) { Hl = 50;  Wl = 50;  loff = 10000; }
        else             { Hl = 25;  Wl = 25;  loff = 12500; }
        float ox = prow[s0 * 2 + 0];
        float oy = prow[s0 * 2 + 1];
        float a  = bf2f(aw[(size_t)bn * 96 + s0]);
        float x = rx * (float)Wl + ox - 0.5f;
        float y = ry * (float)Hl + oy - 0.5f;
        x = fminf(fmaxf(x, -1e4f), 1e4f);
        y = fminf(fmaxf(y, -1e4f), 1e4f);
        float x0f = floorf(x), y0f = floorf(y);
        float lx = x - x0f, ly = y - y0f;
        int x0 = (int)x0f, y0 = (int)y0f;
#pragma unroll
        for (int c = 0; c < 4; c++) {
            int xi = x0 + (c & 1);
            int yi = y0 + (c >> 1);
            bool ok = (xi >= 0) && (xi < Wl) && (yi >= 0) && (yi < Hl);
            int xc = min(max(xi, 0), Wl - 1);
            int yc = min(max(yi, 0), Hl - 1);
            int idx = b * NTOT + loff + yc * Wl + xc;
            float wgt = ((c & 1) ? lx : 1.f - lx) * ((c >> 1) ? ly : 1.f - ly);
            sc[wv][s0][c] = make_uint2(__float_as_uint(ok ? a * wgt : 0.f), (unsigned)(idx * 512));
        }
    }
    __syncthreads();

    const int h = lane >> 3;
    const int dq = (lane & 7) * 4;
    const char* vb = (const char*)val + h * 64 + dq * 2;
    float a0 = 0.f, a1 = 0.f, a2 = 0.f, a3 = 0.f;
#pragma unroll
    for (int lp = 0; lp < 12; lp++) {
        int s = h * 12 + lp;
#pragma unroll
        for (int c = 0; c < 4; c++) {
            uint2 p = sc[wv][s][c];
            float wgt = __uint_as_float(p.x);
            uint2 u = *(const uint2*)(vb + p.y);
            a0 += wgt * __uint_as_float(u.x << 16);
            a1 += wgt * __uint_as_float(u.x & 0xFFFF0000u);
            a2 += wgt * __uint_as_float(u.y << 16);
            a3 += wgt * __uint_as_float(u.y & 0xFFFF0000u);
        }
    }
    uint2 ov;
    ov.x = (unsigned)f2bf(a0) | ((unsigned)f2bf(a1) << 16);
    ov.y = (unsigned)f2bf(a2) | ((unsigned)f2bf(a3) << 16);
    *(uint2*)(out + (size_t)bn * DD + h * 32 + dq) = ov;
}

// ---------------------------------------------------------------------------
extern "C" void kernel_launch(void* const* d_in, const int* in_sizes, int n_in,
                              void* d_out, int out_size, void* d_ws, size_t ws_size,
                              hipStream_t stream) {
    const float* query = (const float*)d_in[0];
    const float* p3    = (const float*)d_in[1];
    const float* p4    = (const float*)d_in[2];
    const float* p5    = (const float*)d_in[3];
    const float* Wv    = (const float*)d_in[4];
    const float* bv    = (const float*)d_in[5];
    const float* Woff  = (const float*)d_in[6];
    const float* boff  = (const float*)d_in[7];
    const float* Wattn = (const float*)d_in[8];
    const float* battn = (const float*)d_in[9];
    const float* Wref  = (const float*)d_in[10];
    const float* bref  = (const float*)d_in[11];
    const float* Wo    = (const float*)d_in[12];
    const float* bo    = (const float*)d_in[13];
    const float* W1    = (const float*)d_in[14];
    const float* b1    = (const float*)d_in[15];
    const float* W2    = (const float*)d_in[16];
    const float* b2    = (const float*)d_in[17];
    const float* g1    = (const float*)d_in[18];
    const float* be1   = (const float*)d_in[19];
    const float* g2    = (const float*)d_in[20];
    const float* be2   = (const float*)d_in[21];
    float* outp = (float*)d_out;

    // ---- workspace layout (bytes), total ~186.9 MB ----
    char* wsb = (char*)d_ws;
    unsigned short* qbf    = (unsigned short*)(wsb + 0);           // 52736x256 bf16  [0, 27000832)
    float*          projb  = (float*)(wsb + 27000832);             // 52736x320 f32   [.., 94502912)
    unsigned short* awb    = (unsigned short*)(wsb + 94502912);    // 52500x96 bf16   [.., 104582912)
    unsigned short* featsb = (unsigned short*)(wsb + 104582912);   // 52736x256 bf16  [.., 131583744)
    unsigned short* valb   = (unsigned short*)(wsb + 131583744);   // 52500x256 bf16  [.., 158463744)
    unsigned short* sampb  = (unsigned short*)(wsb + 158463744);   // 52608x256 bf16  [.., 185399296)
    unsigned short* warena = (unsigned short*)(wsb + 185399296);   // 753664 bf16     [.., 186906624)
    float*          biasq  = (float*)(wsb + 186906624);            // 384 f32
    // NOTE: hid intermediate eliminated — FFN is fused (ffn_k), no 108 MB round-trip.

    unsigned short* Wtq = warena;                 // [384][256]
    unsigned short* Wtv = warena + WTQ_E;
    unsigned short* Wto = warena + WTV_E;
    unsigned short* Wt1 = warena + WTO_E;         // [1024][256]
    unsigned short* Wt2 = warena + WT1_E;         // [256][1024]

    // 1) activation casts
    cast_acts_k<<<dim3(TOTELEMS / 4 / 256), 256, 0, stream>>>(query, p3, p4, p5, qbf, featsb);
    // 2) weight preps (incl. Wref/bref folded into q-proj weight)
    prep_w_k<<<dim3((PREP_TOT + 255) / 256), 256, 0, stream>>>(
        Woff, Wattn, Wref, Wv, Wo, W1, W2, boff, battn, bref, warena, biasq);
    // 3) combined q projection: [off | attn logits | ref logits] -> projb [.,320]
    mm_k<EPI_F32, float><<<dim3(MPAD / 128, 3), 256, 0, stream>>>(
        qbf, Wtq, biasq, projb, MROWS, 256, 290, 320, 0);
    // 4) softmax -> aw bf16
    softmax12_k<<<dim3((MROWS * NHH + 255) / 256), 256, 0, stream>>>(projb, awb);
    // 5) value projection (single dispatch, per-row segment remap)
    mm_k<EPI_VALSEG, unsigned short><<<dim3(MPAD / 128, 2), 256, 0, stream>>>(
        featsb, Wtv, bv, valb, 0, 256, 256, 256, 0);
    // 6) deformable sampling (2 query points per block)
    sample_k<<<dim3(MROWS / 2), 128, 0, stream>>>(valb, projb, awb, sampb);
    // 7) Wo + residual(query f32) + LN1 -> qbf
    gemmln_k<float, unsigned short><<<dim3((MROWS + 63) / 64), 256, 0, stream>>>(
        sampb, Wto, bo, query, g1, be1, qbf, MROWS, 256);
    // 8) fused FFN v2 (8 waves): W1 + GELU + W2 + residual(qbf) + LN2 -> out f32
    ffn_k<<<dim3((MROWS + 63) / 64), 512, 0, stream>>>(
        qbf, Wt1, b1, Wt2, b2, g2, be2, outp, MROWS);
}